// Round 3
// baseline (1869.157 us; speedup 1.0000x reference)
//
#include <hip/hip_runtime.h>
#include <stdint.h>

typedef unsigned short u16;
typedef unsigned int   u32;

#define NN 16384   // nodes
#define NE 262144  // edges
#define NG 64      // graphs
#define HD 256     // hidden

typedef __attribute__((ext_vector_type(8))) short bfrag;  // 8 bf16 (4 VGPR)
typedef __attribute__((ext_vector_type(4))) float ffrag;  // 4 f32 acc

__device__ __forceinline__ float bf2f(u16 h){
  union { u32 u; float f; } v; v.u = ((u32)h) << 16; return v.f;
}
__device__ __forceinline__ u16 f2bf(float x){
  union { float f; u32 u; } v; v.f = x;
  u32 r = v.u + 0x7fffu + ((v.u >> 16) & 1u);
  return (u16)(r >> 16);
}
__device__ __forceinline__ float sigmoidf(float x){ return 1.f/(1.f+__expf(-x)); }

enum { MODE_SCORE=0, MODE_PRE=1, MODE_OUT=2, MODE_OUT_WE=3, MODE_PQ=4 };

__device__ __forceinline__ void load_tile(bfrag (&Ab)[2][8], const u16* __restrict__ A,
                                          long tile, int ml, int q){
  const u16* Ar0 = A + ((size_t)tile*32 + ml)*HD + q*8;
#pragma unroll
  for (int c=0; c<8; ++c){
    Ab[0][c] = *(const bfrag*)(Ar0 + c*32);
    Ab[1][c] = *(const bfrag*)(Ar0 + (size_t)16*HD + c*32);
  }
}

// C[M x 256] = A[M x 256] @ B[256 x 256], A bf16 row-major, B pre-repacked frags.
// R2 restructure (latency-bound fix): B quarter (64 cols) register-resident per
// wave (128 VGPR, loaded once) -> zero B loads in steady state; grid-stride over
// 32-row tiles with double-buffered A registers -> next tile's 16 A-loads are in
// flight during the current tile's 64 MFMAs. ~1 wave/SIMD by design; the per-wave
// pipeline is self-sufficient (no barrier in the K-loop, no LDS for A/B).
template<int MODE>
__global__ __launch_bounds__(256, 1)
void gemm_k(const u16* __restrict__ A, const u16* __restrict__ Bf,
            float* __restrict__ outF, u16* __restrict__ outB,
            const float* __restrict__ bias, const float* __restrict__ vec,
            const float* __restrict__ scal,
            const u16* __restrict__ Pg, const u16* __restrict__ Qg,
            const int* __restrict__ srcI, const int* __restrict__ recvI,
            const float* __restrict__ flags, const float* __restrict__ ht,
            int nTiles)
{
  const int l  = threadIdx.x & 63;
  const int w  = threadIdx.x >> 6;   // wave id = column quarter [w*64, w*64+64)
  const int q  = l >> 4;
  const int ml = l & 15;

  // B quarter resident in registers (8 c-slices x 4 n-tiles)
  bfrag B_r[8][4];
#pragma unroll
  for (int c=0; c<8; ++c)
#pragma unroll
    for (int n=0; n<4; ++n)
      B_r[c][n] = *(const bfrag*)(Bf + (((size_t)(c*16 + w*4 + n))*64 + l)*8);

  // per-lane epilogue constants (hoisted out of the tile loop)
  float bia[4] = {0,0,0,0}, vv[4] = {0,0,0,0}, hh[4] = {0,0,0,0}, tt[4] = {0,0,0,0};
  float sc = 0.f;
  if constexpr (MODE==MODE_SCORE || MODE==MODE_OUT_WE){
#pragma unroll
    for (int n=0; n<4; ++n){ int col=(w*4+n)*16+ml; bia[n]=bias[col]; vv[n]=vec[col]; }
    sc = scal[0];
  }
  if constexpr (MODE==MODE_OUT){
#pragma unroll
    for (int n=0; n<4; ++n) bia[n] = bias[(w*4+n)*16+ml];
  }
  if constexpr (MODE==MODE_PQ){
#pragma unroll
    for (int n=0; n<4; ++n){ int col=(w*4+n)*16+ml;
      bia[n] = bias ? bias[col] : 0.f; hh[n]=ht[col]; tt[n]=ht[HD+col]; }
  }

  __shared__ float sred[4][32];

  auto process = [&](bfrag (&Ab)[2][8], long tile){
    ffrag acc[2][4];
#pragma unroll
    for (int mt=0; mt<2; ++mt)
#pragma unroll
      for (int n=0; n<4; ++n) acc[mt][n] = (ffrag){0.f,0.f,0.f,0.f};

#pragma unroll
    for (int c=0; c<8; ++c)
#pragma unroll
      for (int n=0; n<4; ++n){
        acc[0][n] = __builtin_amdgcn_mfma_f32_16x16x32_bf16(Ab[0][c], B_r[c][n], acc[0][n], 0, 0, 0);
        acc[1][n] = __builtin_amdgcn_mfma_f32_16x16x32_bf16(Ab[1][c], B_r[c][n], acc[1][n], 0, 0, 0);
      }

    if constexpr (MODE==MODE_SCORE || MODE==MODE_OUT_WE){
      float part[2][4] = {{0,0,0,0},{0,0,0,0}};
#pragma unroll
      for (int n=0; n<4; ++n)
#pragma unroll
        for (int mt=0; mt<2; ++mt)
#pragma unroll
          for (int r=0; r<4; ++r){
            float x = acc[mt][n][r] + bia[n];
            if (MODE==MODE_SCORE) x = fmaxf(x, 0.f);
            part[mt][r] += x * vv[n];
          }
#pragma unroll
      for (int mt=0; mt<2; ++mt)
#pragma unroll
        for (int r=0; r<4; ++r){
          float p = part[mt][r];
          p += __shfl_xor(p, 1, 64);
          p += __shfl_xor(p, 2, 64);
          p += __shfl_xor(p, 4, 64);
          p += __shfl_xor(p, 8, 64);
          part[mt][r] = p;
        }
      if (ml == 0){
#pragma unroll
        for (int mt=0; mt<2; ++mt)
#pragma unroll
          for (int r=0; r<4; ++r)
            sred[w][mt*16 + q*4 + r] = part[mt][r];
      }
      __syncthreads();
      if (threadIdx.x < 32){
        const int t = threadIdx.x;
        float v = sred[0][t] + sred[1][t] + sred[2][t] + sred[3][t];
        outF[tile*32 + t] = sigmoidf(v + sc);
      }
      __syncthreads();
    } else if constexpr (MODE==MODE_OUT){
#pragma unroll
      for (int mt=0; mt<2; ++mt)
#pragma unroll
        for (int r=0; r<4; ++r){
          long row = tile*32 + mt*16 + q*4 + r;
          u16* op = outB + (size_t)row*HD + w*64 + ml;
#pragma unroll
          for (int n=0; n<4; ++n)
            op[n*16] = f2bf(acc[mt][n][r] + bia[n]);
        }
    } else if constexpr (MODE==MODE_PRE){
      // h = relu(b_e@W1c + P[src] + Q[recv]); P/Q are quarter-interleaved:
      // stored[row][w*64+ml*4+n] = math[row][(w*4+n)*16+ml] -> one uint2 per row
#pragma unroll
      for (int mt=0; mt<2; ++mt)
#pragma unroll
        for (int r=0; r<4; ++r){
          long row = tile*32 + mt*16 + q*4 + r;
          const int si = srcI[row];
          const int ri = recvI[row];
          uint2 pu = *(const uint2*)(Pg + (size_t)si*HD + w*64 + ml*4);
          uint2 qu = *(const uint2*)(Qg + (size_t)ri*HD + w*64 + ml*4);
          float pv[4] = { bf2f((u16)(pu.x & 0xffff)), bf2f((u16)(pu.x >> 16)),
                          bf2f((u16)(pu.y & 0xffff)), bf2f((u16)(pu.y >> 16)) };
          float qv[4] = { bf2f((u16)(qu.x & 0xffff)), bf2f((u16)(qu.x >> 16)),
                          bf2f((u16)(qu.y & 0xffff)), bf2f((u16)(qu.y >> 16)) };
          u16* op = outB + (size_t)row*HD + w*64 + ml;
#pragma unroll
          for (int n=0; n<4; ++n){
            float v = acc[mt][n][r] + pv[n] + qv[n];
            op[n*16] = f2bf(fmaxf(v, 0.f));
          }
        }
    } else { // MODE_PQ: node GEMM + rank-1 head/tail; output quarter-interleaved
#pragma unroll
      for (int mt=0; mt<2; ++mt)
#pragma unroll
        for (int r=0; r<4; ++r){
          long row = tile*32 + mt*16 + q*4 + r;
          const float fh = flags[2*row];
          const float ft = flags[2*row+1];
          u16 o[4];
#pragma unroll
          for (int n=0; n<4; ++n)
            o[n] = f2bf(acc[mt][n][r] + fh*hh[n] + ft*tt[n] + bia[n]);
          uint2 pk; pk.x = (u32)o[0] | ((u32)o[1] << 16);
          pk.y = (u32)o[2] | ((u32)o[3] << 16);
          *(uint2*)(outB + (size_t)row*HD + w*64 + ml*4) = pk;
        }
    }
  };

  bfrag A0[2][8], A1[2][8];
  long tile = blockIdx.x;
  const long step = gridDim.x;
  load_tile(A0, A, tile, ml, q);
  for (;;){
    long t1 = tile + step;
    if (t1 < nTiles) load_tile(A1, A, t1, ml, q);
    process(A0, tile);
    if (t1 >= nTiles) break;
    long t2 = t1 + step;
    if (t2 < nTiles) load_tile(A0, A, t2, ml, q);
    process(A1, t1);
    if (t2 >= nTiles) break;
    tile = t2;
  }
}

// repack B[256 x 256] f32 row-major -> bf16 MFMA-fragment order:
// out[((c*16+n)*64+l)*8+j] = B[c*32+(l>>4)*8+j][n*16+(l&15)]
__global__ void repack_k(const float* __restrict__ B, u16* __restrict__ out){
  int t = blockIdx.x*256 + threadIdx.x;        // 8192 total
  int l = t & 63, n = (t>>6)&15, c = t>>10;
  int k0 = c*32 + ((l>>4)<<3), col = n*16 + (l&15);
#pragma unroll
  for (int j=0; j<8; ++j)
    out[(size_t)t*8 + j] = f2bf(B[(size_t)(k0+j)*HD + col]);
}

// b_e(iter0) = [edge_features | g_all] -> bf16 row-major
__global__ void initbe_k(const float* __restrict__ ef, const float* __restrict__ gall,
                         u16* __restrict__ BE){
  int t = blockIdx.x*256 + threadIdx.x;        // NE*64
  int e = t >> 6; int c4 = (t & 63) * 4;
  float4 v;
  if (c4 < 192) v = *(const float4*)(ef + (size_t)e*192 + c4);
  else          v = *(const float4*)(gall + (c4 - 192));
  u32 lo = (u32)f2bf(v.x) | ((u32)f2bf(v.y) << 16);
  u32 hi = (u32)f2bf(v.z) | ((u32)f2bf(v.w) << 16);
  uint2 o; o.x = lo; o.y = hi;
  *(uint2*)(BE + (size_t)e*HD + c4) = o;
}

__global__ void flags_k(const int* __restrict__ batch, const int* __restrict__ heads,
                        const int* __restrict__ tails, float* __restrict__ flags){
  int n = blockIdx.x*256 + threadIdx.x;
  int g = batch[n];
  flags[2*n]   = (n == heads[g]) ? 1.f : 0.f;
  flags[2*n+1] = (n == tails[g]) ? 1.f : 0.f;
}

// exclusive prefix sum of degrees -> CSR offsets (+ cursor copy), single block
__global__ void scan_k(const int* __restrict__ deg, int* __restrict__ offs,
                       int* __restrict__ cur){
  __shared__ int part[256];
  int tid = threadIdx.x;
  int base = tid * 64;
  int s = 0;
  for (int j=0; j<64; ++j) s += deg[base+j];
  part[tid] = s;
  __syncthreads();
  if (tid == 0){
    int run = 0;
    for (int i=0; i<256; ++i){ int t = part[i]; part[i] = run; run += t; }
  }
  __syncthreads();
  int run = part[tid];
  for (int j=0; j<64; ++j){
    offs[base+j] = run; cur[base+j] = run; run += deg[base+j];
  }
  if (tid == 255) offs[NN] = run;
}

__global__ void fill_k(const int* __restrict__ recv, int* __restrict__ cur,
                       int* __restrict__ eids){
  int e = blockIdx.x*256 + threadIdx.x;
  int r = recv[e];
  int p = atomicAdd(&cur[r], 1);
  eids[p] = e;
}

// per-node softmax over incoming edges + weighted aggregation, one wave per node
__global__ __launch_bounds__(256)
void agg_k(const float* __restrict__ score, const u16* __restrict__ BE,
           const int* __restrict__ offs, const int* __restrict__ eids,
           float* __restrict__ bv, u16* __restrict__ bvb){
  int node = blockIdx.x*4 + (threadIdx.x >> 6);
  int l = threadIdx.x & 63;
  int beg = offs[node], end = offs[node+1];

  float m = -1e30f;
  for (int i=beg+l; i<end; i+=64) m = fmaxf(m, score[eids[i]]);
#pragma unroll
  for (int d=1; d<64; d<<=1) m = fmaxf(m, __shfl_xor(m, d, 64));

  float s = 0.f;
  for (int i=beg+l; i<end; i+=64) s += __expf(score[eids[i]] - m);
#pragma unroll
  for (int d=1; d<64; d<<=1) s += __shfl_xor(s, d, 64);

  float deg = (float)(end - beg);
  float scale = (end > beg) ? (1.f/s) * (1.f/(1.f+deg)) : 0.f;

  float a0=0.f, a1=0.f, a2=0.f, a3=0.f;
  for (int i=beg; i<end; ++i){
    int e = eids[i];
    float al = __expf(score[e] - m);
    uint2 uv = *(const uint2*)(BE + (size_t)e*HD + l*4);
    a0 += al * bf2f((u16)(uv.x & 0xffff));
    a1 += al * bf2f((u16)(uv.x >> 16));
    a2 += al * bf2f((u16)(uv.y & 0xffff));
    a3 += al * bf2f((u16)(uv.y >> 16));
  }
  size_t o = (size_t)node*HD + l*4;
  a0 *= scale; a1 *= scale; a2 *= scale; a3 *= scale;
  bv[o+0]=a0; bv[o+1]=a1; bv[o+2]=a2; bv[o+3]=a3;
  uint2 p; p.x = (u32)f2bf(a0) | ((u32)f2bf(a1)<<16);
  p.y = (u32)f2bf(a2) | ((u32)f2bf(a3)<<16);
  *(uint2*)(bvb + o) = p;
}

// graph head: g_max + gather head/tail rows -> g_G [64][768] f32
__global__ void gmax_k(const float* __restrict__ bv, const int* __restrict__ heads,
                       const int* __restrict__ tails, float* __restrict__ gG){
  int g = blockIdx.x, col = threadIdx.x;
  float mx = -1e30f;
  const float* p = bv + (size_t)g*256*HD + col;
  for (int i=0; i<256; ++i) mx = fmaxf(mx, p[(size_t)i*HD]);
  gG[g*768 + col]       = mx;
  gG[g*768 + 256 + col] = bv[(size_t)heads[g]*HD + col];
  gG[g*768 + 512 + col] = bv[(size_t)tails[g]*HD + col];
}

__global__ void glog_k(const float* __restrict__ gG, const float* __restrict__ w1,
                       const float* __restrict__ b1, const float* __restrict__ w2,
                       const float* __restrict__ b2, float* __restrict__ logits){
  int g = blockIdx.x, n = threadIdx.x;
  float a = b1[n];
  const float* gg = gG + g*768;
  for (int k=0; k<768; ++k) a += gg[k] * w1[(size_t)k*HD + n];
  a = fmaxf(a, 0.f) * w2[n];
#pragma unroll
  for (int d=1; d<64; d<<=1) a += __shfl_xor(a, d, 64);
  __shared__ float red[4];
  if ((threadIdx.x & 63) == 0) red[threadIdx.x >> 6] = a;
  __syncthreads();
  if (threadIdx.x == 0) logits[g] = red[0]+red[1]+red[2]+red[3] + b2[0];
}

__global__ void gfin_k(const float* __restrict__ gG, const float* __restrict__ logits,
                       float* __restrict__ out){
  int tid = threadIdx.x;
  float m = -1e30f;
  for (int g=0; g<NG; ++g) m = fmaxf(m, logits[g]);
  float s = 0.f;
  for (int g=0; g<NG; ++g) s += __expf(logits[g] - m);
  float inv = 1.f/s;
  for (int j=tid; j<768; j+=256){
    float o = 0.f;
    for (int g=0; g<NG; ++g) o += __expf(logits[g]-m)*inv * gG[g*768 + j];
    out[j] = o;
  }
}

extern "C" void kernel_launch(void* const* d_in, const int* in_sizes, int n_in,
                              void* d_out, int out_size, void* d_ws, size_t ws_size,
                              hipStream_t stream)
{
  const float* ef    = (const float*)d_in[0];
  const float* gall  = (const float*)d_in[1];
  const float* ea_w1 = (const float*)d_in[2];
  const float* ea_b1 = (const float*)d_in[3];
  const float* ea_w2 = (const float*)d_in[4];
  const float* ea_b2 = (const float*)d_in[5];
  const float* eu_w1 = (const float*)d_in[6];
  const float* eu_b1 = (const float*)d_in[7];
  const float* eu_w2 = (const float*)d_in[8];
  const float* eu_b2 = (const float*)d_in[9];
  const float* gw_w1 = (const float*)d_in[10];
  const float* gw_b1 = (const float*)d_in[11];
  const float* gw_w2 = (const float*)d_in[12];
  const float* gw_b2 = (const float*)d_in[13];
  const float* ew_w  = (const float*)d_in[14];
  const float* ew_b  = (const float*)d_in[15];
  const int* eidx    = (const int*)d_in[16];
  const int* srcI    = eidx;
  const int* recvI   = eidx + NE;
  const int* ndeg    = (const int*)d_in[17];
  const int* batch   = (const int*)d_in[18];
  const int* heads   = (const int*)d_in[19];
  const int* tails   = (const int*)d_in[20];
  float* out = (float*)d_out;

  char* wsb = (char*)d_ws;
  size_t off = 0;
  auto alloc = [&](size_t sz)->char*{
    char* p = wsb + off; off = (off + sz + 255) & ~(size_t)255; return p;
  };
  u16*   BE    = (u16*)  alloc((size_t)NE*HD*2);
  u16*   Hh    = (u16*)  alloc((size_t)NE*HD*2);
  float* score = (float*)alloc((size_t)NE*4);
  u16*   P     = (u16*)  alloc((size_t)NN*HD*2);
  u16*   Q     = (u16*)  alloc((size_t)NN*HD*2);
  float* bv    = (float*)alloc((size_t)NN*HD*4);
  u16*   bvb   = (u16*)  alloc((size_t)NN*HD*2);
  int*   offs  = (int*)  alloc((size_t)(NN+1)*4);
  int*   cur   = (int*)  alloc((size_t)NN*4);
  int*   eids  = (int*)  alloc((size_t)NE*4);
  float* flags = (float*)alloc((size_t)NN*8);
  u16*   eaw1f = (u16*)  alloc((size_t)65536*2);
  u16*   w1af  = (u16*)  alloc((size_t)65536*2);
  u16*   w1bf  = (u16*)  alloc((size_t)65536*2);
  u16*   w1cf  = (u16*)  alloc((size_t)65536*2);
  u16*   euw2f = (u16*)  alloc((size_t)65536*2);
  float* gG    = (float*)alloc((size_t)NG*768*4);
  float* logits= (float*)alloc((size_t)NG*4);

  // one-time per launch: weight repacks + b_e init + flags + CSR
  repack_k<<<32,256,0,stream>>>(ea_w1, eaw1f);
  repack_k<<<32,256,0,stream>>>(eu_w1, w1af);              // rows 0..255   (src b_v part)
  repack_k<<<32,256,0,stream>>>(eu_w1 + 258*HD, w1bf);     // rows 258..513 (recv b_v part)
  repack_k<<<32,256,0,stream>>>(eu_w1 + 516*HD, w1cf);     // rows 516..771 (b_e part)
  repack_k<<<32,256,0,stream>>>(eu_w2, euw2f);
  initbe_k<<<NE*64/256,256,0,stream>>>(ef, gall, BE);
  flags_k<<<NN/256,256,0,stream>>>(batch, heads, tails, flags);
  scan_k<<<1,256,0,stream>>>(ndeg, offs, cur);
  fill_k<<<NE/256,256,0,stream>>>(recvI, cur, eids);

  const int NT_E = NE/32;   // 8192 row-tiles for edge GEMMs
  const int NT_N = NN/32;   // 512 row-tiles for node GEMMs
  const int GRID_E = 1024;  // 8 tiles per block (even -> clean 2-unrolled loop)
  const int GRID_N = 512;

  for (int it=0; it<3; ++it){
    // score = sigmoid(relu(b_e@ea_w1+b1)@ea_w2+b2), second layer fused in-register
    gemm_k<MODE_SCORE><<<GRID_E,256,0,stream>>>(BE, eaw1f, score, nullptr,
        ea_b1, ea_w2, ea_b2, nullptr, nullptr, nullptr, nullptr, nullptr, nullptr, NT_E);
    // scatter-softmax + degree-normalized aggregation -> b_v (f32 + bf16)
    agg_k<<<NN/4,256,0,stream>>>(score, BE, offs, eids, bv, bvb);
    // P = r_v@W1a + b1 ; Q = r_v@W1b  (head/tail rank-1 rows in epilogue)
    gemm_k<MODE_PQ><<<GRID_N,256,0,stream>>>(bvb, w1af, nullptr, P,
        eu_b1, nullptr, nullptr, nullptr, nullptr, nullptr, nullptr, flags, eu_w1 + 256*HD, NT_N);
    gemm_k<MODE_PQ><<<GRID_N,256,0,stream>>>(bvb, w1bf, nullptr, Q,
        nullptr, nullptr, nullptr, nullptr, nullptr, nullptr, nullptr, flags, eu_w1 + 514*HD, NT_N);
    // h = relu(b_e@W1c + P[src] + Q[recv])
    gemm_k<MODE_PRE><<<GRID_E,256,0,stream>>>(BE, w1cf, nullptr, Hh,
        nullptr, nullptr, nullptr, P, Q, srcI, recvI, nullptr, nullptr, NT_E);
    if (it < 2){
      // b_e = h@eu_w2 + b2
      gemm_k<MODE_OUT><<<GRID_E,256,0,stream>>>(Hh, euw2f, nullptr, BE,
          eu_b2, nullptr, nullptr, nullptr, nullptr, nullptr, nullptr, nullptr, nullptr, NT_E);
    } else {
      // final iter: fuse w_e = sigmoid((h@eu_w2+b2)@ew_w+ew_b); b_e never stored
      gemm_k<MODE_OUT_WE><<<GRID_E,256,0,stream>>>(Hh, euw2f, out, nullptr,
          eu_b2, ew_w, ew_b, nullptr, nullptr, nullptr, nullptr, nullptr, nullptr, NT_E);
    }
  }

  // graph head (f32 exact, tiny)
  gmax_k<<<NG,256,0,stream>>>(bv, heads, tails, gG);
  glog_k<<<NG,256,0,stream>>>(gG, gw_w1, gw_b1, gw_w2, gw_b2, logits);
  gfin_k<<<1,256,0,stream>>>(gG, logits, out + NE);
}

// Round 4
// 1285.916 us; speedup vs baseline: 1.4536x; 1.4536x over previous
//
#include <hip/hip_runtime.h>
#include <stdint.h>

typedef unsigned short u16;
typedef unsigned int   u32;

#define NN 16384   // nodes
#define NE 262144  // edges
#define NG 64      // graphs
#define HD 256     // hidden

typedef __attribute__((ext_vector_type(8))) short bfrag;  // 8 bf16 (4 VGPR)
typedef __attribute__((ext_vector_type(4))) float ffrag;  // 4 f32 acc

__device__ __forceinline__ float bf2f(u16 h){
  union { u32 u; float f; } v; v.u = ((u32)h) << 16; return v.f;
}
__device__ __forceinline__ u16 f2bf(float x){
  union { float f; u32 u; } v; v.f = x;
  u32 r = v.u + 0x7fffu + ((v.u >> 16) & 1u);
  return (u16)(r >> 16);
}
__device__ __forceinline__ float sigmoidf(float x){ return 1.f/(1.f+__expf(-x)); }

// async global->LDS DMA, 16B per lane: lane i lands at (uniform lds base) + i*16
__device__ __forceinline__ void dma16(const void* g, void* l){
  __builtin_amdgcn_global_load_lds(
      (const __attribute__((address_space(1))) u32*)g,
      (__attribute__((address_space(3))) u32*)l, 16, 0, 0);
}

// Feature permutation pi: hidden vectors are stored with feature f at position
// p(f) = (f>>6)*64 + (f&15)*4 + ((f>>4)&3). inv(p) = (p>>6)*64 + (p&3)*16 + ((p>>2)&15).
// Weights are repacked with K-rows permuted by inv() so GEMMs contract correctly.
// Payoff: every epilogue writes packed uint2 (4 consecutive positions = this lane's
// 4 n-values) and the PRE P/Q gather is one uint2 per row instead of 4 strided u16.

enum { MODE_SCORE=0, MODE_PRE=1, MODE_OUT=2, MODE_OUT_WE=3, MODE_PQ=4 };

// C[M x 256] = A[M x 256] @ B[256 x 256]; A bf16 row-major (position space),
// B pre-repacked frag layout [c][n][lane][8].
// R3->R4: m97-style LDS-fed GEMM. Block 256 thr = 4 waves; tile 64 rows x 256 cols;
// K in 8 steps of 32. Per step: stage A(4KB)+B(16KB) via global_load_lds (5 DMA
// instr/wave), barrier, 8x ds_read_b128 + 16 MFMA per wave, barrier. Fragment
// feed moves from the ~64B/cyc VMEM port (R2's measured 11% MfmaUtil ceiling)
// to LDS at 256B/cyc.
template<int MODE>
__global__ __launch_bounds__(256, 3)
void gemm_k(const u16* __restrict__ A, const u16* __restrict__ Bf,
            float* __restrict__ outF, u16* __restrict__ outB,
            const float* __restrict__ bias, const float* __restrict__ vec,
            const float* __restrict__ scal,
            const u16* __restrict__ Pg, const u16* __restrict__ Qg,
            const int* __restrict__ srcI, const int* __restrict__ recvI,
            const float* __restrict__ flags, const float* __restrict__ ht)
{
  __shared__ __align__(16) u16 sA[64*32];     // [row 64][k 32]  (4KB)
  __shared__ __align__(16) u16 sB[16*64*8];   // [n 16][lane 64][8] (16KB)
  __shared__ float sred[4][64];

  const int l  = threadIdx.x & 63;
  const int w  = threadIdx.x >> 6;   // wave: col band [w*64, w*64+64)
  const int q  = l >> 4;
  const int ml = l & 15;
  const long rowBase = (long)blockIdx.x * 64;

  // DMA source/dest (A: wave w stages rows 16w..16w+15; lane l -> row 16w+(l>>2), 16B chunk l&3)
  const u16* gA = A + (size_t)(rowBase + 16*w + (l>>2))*HD + (l&3)*8;
  u16* lA = sA + w*512;                         // + lane*8 implicit
  const u16* gB = Bf + (size_t)l*8;

  ffrag acc[4][4];
#pragma unroll
  for (int mt=0; mt<4; ++mt)
#pragma unroll
    for (int n=0; n<4; ++n) acc[mt][n] = (ffrag){0.f,0.f,0.f,0.f};

  // per-lane epilogue constants (original col = (w*4+n)*16 + ml)
  float bia[4] = {0,0,0,0}, vv[4] = {0,0,0,0}, hh[4] = {0,0,0,0}, tt[4] = {0,0,0,0};
  float sc = 0.f;
  if constexpr (MODE==MODE_SCORE || MODE==MODE_OUT_WE){
#pragma unroll
    for (int n=0; n<4; ++n){ int col=(w*4+n)*16+ml; bia[n]=bias[col]; vv[n]=vec[col]; }
    sc = scal[0];
  }
  if constexpr (MODE==MODE_OUT){
#pragma unroll
    for (int n=0; n<4; ++n) bia[n] = bias[(w*4+n)*16+ml];
  }
  if constexpr (MODE==MODE_PQ){
#pragma unroll
    for (int n=0; n<4; ++n){ int col=(w*4+n)*16+ml;
      bia[n] = bias ? bias[col] : 0.f; hh[n]=ht[col]; tt[n]=ht[HD+col]; }
  }

#pragma unroll 1
  for (int c=0; c<8; ++c){
    // stage K-step c (5 DMA instructions per wave)
    dma16(gA + c*32, lA);
#pragma unroll
    for (int t=0; t<4; ++t)
      dma16(gB + (size_t)c*8192 + (w*4+t)*512, sB + (w*4+t)*512);
    __syncthreads();   // compiler drains vmcnt before barrier -> stage complete

    bfrag a[4], b[4];
#pragma unroll
    for (int mt=0; mt<4; ++mt) a[mt] = *(const bfrag*)(sA + (mt*16+ml)*32 + q*8);
#pragma unroll
    for (int n=0; n<4; ++n)    b[n]  = *(const bfrag*)(sB + ((w*4+n)*64 + l)*8);
#pragma unroll
    for (int mt=0; mt<4; ++mt)
#pragma unroll
      for (int n=0; n<4; ++n)
        acc[mt][n] = __builtin_amdgcn_mfma_f32_16x16x32_bf16(a[mt], b[n], acc[mt][n], 0, 0, 0);
    __syncthreads();   // readers done before next stage overwrites
  }

  if constexpr (MODE==MODE_SCORE || MODE==MODE_OUT_WE){
    float part[4][4];
#pragma unroll
    for (int mt=0; mt<4; ++mt)
#pragma unroll
      for (int r=0; r<4; ++r) part[mt][r] = 0.f;
#pragma unroll
    for (int n=0; n<4; ++n)
#pragma unroll
      for (int mt=0; mt<4; ++mt)
#pragma unroll
        for (int r=0; r<4; ++r){
          float x = acc[mt][n][r] + bia[n];
          if (MODE==MODE_SCORE) x = fmaxf(x, 0.f);
          part[mt][r] += x * vv[n];
        }
#pragma unroll
    for (int mt=0; mt<4; ++mt)
#pragma unroll
      for (int r=0; r<4; ++r){
        float p = part[mt][r];
        p += __shfl_xor(p, 1, 64);
        p += __shfl_xor(p, 2, 64);
        p += __shfl_xor(p, 4, 64);
        p += __shfl_xor(p, 8, 64);
        part[mt][r] = p;
      }
    if (ml == 0){
#pragma unroll
      for (int mt=0; mt<4; ++mt)
#pragma unroll
        for (int r=0; r<4; ++r)
          sred[w][mt*16 + q*4 + r] = part[mt][r];
    }
    __syncthreads();
    if (threadIdx.x < 64){
      const int t = threadIdx.x;
      float v = sred[0][t] + sred[1][t] + sred[2][t] + sred[3][t];
      outF[rowBase + t] = sigmoidf(v + sc);
    }
  } else if constexpr (MODE==MODE_OUT){
#pragma unroll
    for (int mt=0; mt<4; ++mt)
#pragma unroll
      for (int r=0; r<4; ++r){
        long row = rowBase + mt*16 + q*4 + r;
        u16 o[4];
#pragma unroll
        for (int n=0; n<4; ++n) o[n] = f2bf(acc[mt][n][r] + bia[n]);
        uint2 pk; pk.x = (u32)o[0] | ((u32)o[1]<<16); pk.y = (u32)o[2] | ((u32)o[3]<<16);
        *(uint2*)(outB + (size_t)row*HD + w*64 + ml*4) = pk;
      }
  } else if constexpr (MODE==MODE_PRE){
    // h = relu(b_e@W1c + P[src] + Q[recv]); P/Q position-packed: one uint2 per row
#pragma unroll
    for (int mt=0; mt<4; ++mt)
#pragma unroll
      for (int r=0; r<4; ++r){
        long row = rowBase + mt*16 + q*4 + r;
        const int si = srcI[row];
        const int ri = recvI[row];
        uint2 pu = *(const uint2*)(Pg + (size_t)si*HD + w*64 + ml*4);
        uint2 qu = *(const uint2*)(Qg + (size_t)ri*HD + w*64 + ml*4);
        float pv[4] = { bf2f((u16)(pu.x & 0xffff)), bf2f((u16)(pu.x >> 16)),
                        bf2f((u16)(pu.y & 0xffff)), bf2f((u16)(pu.y >> 16)) };
        float qv[4] = { bf2f((u16)(qu.x & 0xffff)), bf2f((u16)(qu.x >> 16)),
                        bf2f((u16)(qu.y & 0xffff)), bf2f((u16)(qu.y >> 16)) };
        u16 o[4];
#pragma unroll
        for (int n=0; n<4; ++n)
          o[n] = f2bf(fmaxf(acc[mt][n][r] + pv[n] + qv[n], 0.f));
        uint2 pk; pk.x = (u32)o[0] | ((u32)o[1]<<16); pk.y = (u32)o[2] | ((u32)o[3]<<16);
        *(uint2*)(outB + (size_t)row*HD + w*64 + ml*4) = pk;
      }
  } else { // MODE_PQ
#pragma unroll
    for (int mt=0; mt<4; ++mt)
#pragma unroll
      for (int r=0; r<4; ++r){
        long row = rowBase + mt*16 + q*4 + r;
        const float fh = flags[2*row];
        const float ft = flags[2*row+1];
        u16 o[4];
#pragma unroll
        for (int n=0; n<4; ++n)
          o[n] = f2bf(acc[mt][n][r] + fh*hh[n] + ft*tt[n] + bia[n]);
        uint2 pk; pk.x = (u32)o[0] | ((u32)o[1]<<16); pk.y = (u32)o[2] | ((u32)o[3]<<16);
        *(uint2*)(outB + (size_t)row*HD + w*64 + ml*4) = pk;
      }
  }
}

// repack B[256 x 256] f32 row-major -> bf16 frag layout [c][n][lane][8],
// with K-rows permuted: packed row k_pos takes source feature inv(k_pos).
__global__ void repack_k(const float* __restrict__ B, u16* __restrict__ out){
  int t = blockIdx.x*256 + threadIdx.x;        // 8192 total
  int l = t & 63, n = (t>>6)&15, c = t>>10;
  int col = n*16 + (l&15);
  int kbase = c*32 + ((l>>4)<<3);
#pragma unroll
  for (int j=0; j<8; ++j){
    int kp = kbase + j;
    int f = (kp>>6)*64 + (kp&3)*16 + ((kp>>2)&15);   // inv(kp)
    out[(size_t)t*8 + j] = f2bf(B[(size_t)f*HD + col]);
  }
}

// b_e(iter0) = [edge_features | g_all] -> bf16, position-permuted layout
__global__ void initbe_k(const float* __restrict__ ef, const float* __restrict__ gall,
                         u16* __restrict__ BE){
  int t = blockIdx.x*256 + threadIdx.x;        // NE*64
  int e = t >> 6; int p4 = (t & 63) * 4;
  int w64 = p4 >> 6, mlr = (p4 >> 2) & 15;
  u16 o[4];
#pragma unroll
  for (int i=0; i<4; ++i){
    int f = w64*64 + i*16 + mlr;                 // inv(p4+i)
    float v = (f < 192) ? ef[(size_t)e*192 + f] : gall[f - 192];
    o[i] = f2bf(v);
  }
  uint2 pk; pk.x = (u32)o[0] | ((u32)o[1]<<16); pk.y = (u32)o[2] | ((u32)o[3]<<16);
  *(uint2*)(BE + (size_t)e*HD + p4) = pk;
}

__global__ void flags_k(const int* __restrict__ batch, const int* __restrict__ heads,
                        const int* __restrict__ tails, float* __restrict__ flags){
  int n = blockIdx.x*256 + threadIdx.x;
  int g = batch[n];
  flags[2*n]   = (n == heads[g]) ? 1.f : 0.f;
  flags[2*n+1] = (n == tails[g]) ? 1.f : 0.f;
}

// exclusive prefix sum of degrees -> CSR offsets (+ cursor copy), single block
__global__ void scan_k(const int* __restrict__ deg, int* __restrict__ offs,
                       int* __restrict__ cur){
  __shared__ int part[256];
  int tid = threadIdx.x;
  int base = tid * 64;
  int s = 0;
  for (int j=0; j<64; ++j) s += deg[base+j];
  part[tid] = s;
  __syncthreads();
  if (tid == 0){
    int run = 0;
    for (int i=0; i<256; ++i){ int t = part[i]; part[i] = run; run += t; }
  }
  __syncthreads();
  int run = part[tid];
  for (int j=0; j<64; ++j){
    offs[base+j] = run; cur[base+j] = run; run += deg[base+j];
  }
  if (tid == 255) offs[NN] = run;
}

__global__ void fill_k(const int* __restrict__ recv, int* __restrict__ cur,
                       int* __restrict__ eids){
  int e = blockIdx.x*256 + threadIdx.x;
  int r = recv[e];
  int p = atomicAdd(&cur[r], 1);
  eids[p] = e;
}

// per-node softmax over incoming edges + weighted aggregation, one wave per node
__global__ __launch_bounds__(256)
void agg_k(const float* __restrict__ score, const u16* __restrict__ BE,
           const int* __restrict__ offs, const int* __restrict__ eids,
           float* __restrict__ bv, u16* __restrict__ bvb){
  int node = blockIdx.x*4 + (threadIdx.x >> 6);
  int l = threadIdx.x & 63;
  int beg = offs[node], end = offs[node+1];

  float m = -1e30f;
  for (int i=beg+l; i<end; i+=64) m = fmaxf(m, score[eids[i]]);
#pragma unroll
  for (int d=1; d<64; d<<=1) m = fmaxf(m, __shfl_xor(m, d, 64));

  float s = 0.f;
  for (int i=beg+l; i<end; i+=64) s += __expf(score[eids[i]] - m);
#pragma unroll
  for (int d=1; d<64; d<<=1) s += __shfl_xor(s, d, 64);

  float deg = (float)(end - beg);
  float scale = (end > beg) ? (1.f/s) * (1.f/(1.f+deg)) : 0.f;

  float a0=0.f, a1=0.f, a2=0.f, a3=0.f;
  for (int i=beg; i<end; ++i){
    int e = eids[i];
    float al = __expf(score[e] - m);
    uint2 uv = *(const uint2*)(BE + (size_t)e*HD + l*4);
    a0 += al * bf2f((u16)(uv.x & 0xffff));
    a1 += al * bf2f((u16)(uv.x >> 16));
    a2 += al * bf2f((u16)(uv.y & 0xffff));
    a3 += al * bf2f((u16)(uv.y >> 16));
  }
  size_t o = (size_t)node*HD + l*4;
  a0 *= scale; a1 *= scale; a2 *= scale; a3 *= scale;
  bv[o+0]=a0; bv[o+1]=a1; bv[o+2]=a2; bv[o+3]=a3;
  uint2 p; p.x = (u32)f2bf(a0) | ((u32)f2bf(a1)<<16);
  p.y = (u32)f2bf(a2) | ((u32)f2bf(a3)<<16);
  *(uint2*)(bvb + o) = p;
}

// graph head: g_max + gather head/tail rows -> g_G [64][768] f32 (position space)
__global__ void gmax_k(const float* __restrict__ bv, const int* __restrict__ heads,
                       const int* __restrict__ tails, float* __restrict__ gG){
  int g = blockIdx.x, col = threadIdx.x;
  float mx = -1e30f;
  const float* p = bv + (size_t)g*256*HD + col;
  for (int i=0; i<256; ++i) mx = fmaxf(mx, p[(size_t)i*HD]);
  gG[g*768 + col]       = mx;
  gG[g*768 + 256 + col] = bv[(size_t)heads[g]*HD + col];
  gG[g*768 + 512 + col] = bv[(size_t)tails[g]*HD + col];
}

__global__ void glog_k(const float* __restrict__ gG, const float* __restrict__ w1,
                       const float* __restrict__ b1, const float* __restrict__ w2,
                       const float* __restrict__ b2, float* __restrict__ logits){
  int g = blockIdx.x, n = threadIdx.x;
  float a = b1[n];
  const float* gg = gG + g*768;
  for (int k=0; k<768; ++k){
    int b = k >> 8, p = k & 255;
    int f = (p>>6)*64 + (p&3)*16 + ((p>>2)&15);   // inv(p)
    a += gg[k] * w1[(size_t)(b*256 + f)*HD + n];
  }
  a = fmaxf(a, 0.f) * w2[n];
#pragma unroll
  for (int d=1; d<64; d<<=1) a += __shfl_xor(a, d, 64);
  __shared__ float red[4];
  if ((threadIdx.x & 63) == 0) red[threadIdx.x >> 6] = a;
  __syncthreads();
  if (threadIdx.x == 0) logits[g] = red[0]+red[1]+red[2]+red[3] + b2[0];
}

__global__ void gfin_k(const float* __restrict__ gG, const float* __restrict__ logits,
                       float* __restrict__ out){
  int tid = threadIdx.x;
  float m = -1e30f;
  for (int g=0; g<NG; ++g) m = fmaxf(m, logits[g]);
  float s = 0.f;
  for (int g=0; g<NG; ++g) s += __expf(logits[g] - m);
  float inv = 1.f/s;
  for (int j=tid; j<768; j+=256){
    int b = j >> 8, f = j & 255;
    int p = (f>>6)*64 + (f&15)*4 + ((f>>4)&3);    // pi(f): un-permute for output
    float o = 0.f;
    for (int g=0; g<NG; ++g) o += __expf(logits[g]-m)*inv * gG[g*768 + b*256 + p];
    out[j] = o;
  }
}

extern "C" void kernel_launch(void* const* d_in, const int* in_sizes, int n_in,
                              void* d_out, int out_size, void* d_ws, size_t ws_size,
                              hipStream_t stream)
{
  const float* ef    = (const float*)d_in[0];
  const float* gall  = (const float*)d_in[1];
  const float* ea_w1 = (const float*)d_in[2];
  const float* ea_b1 = (const float*)d_in[3];
  const float* ea_w2 = (const float*)d_in[4];
  const float* ea_b2 = (const float*)d_in[5];
  const float* eu_w1 = (const float*)d_in[6];
  const float* eu_b1 = (const float*)d_in[7];
  const float* eu_w2 = (const float*)d_in[8];
  const float* eu_b2 = (const float*)d_in[9];
  const float* gw_w1 = (const float*)d_in[10];
  const float* gw_b1 = (const float*)d_in[11];
  const float* gw_w2 = (const float*)d_in[12];
  const float* gw_b2 = (const float*)d_in[13];
  const float* ew_w  = (const float*)d_in[14];
  const float* ew_b  = (const float*)d_in[15];
  const int* eidx    = (const int*)d_in[16];
  const int* srcI    = eidx;
  const int* recvI   = eidx + NE;
  const int* ndeg    = (const int*)d_in[17];
  const int* batch   = (const int*)d_in[18];
  const int* heads   = (const int*)d_in[19];
  const int* tails   = (const int*)d_in[20];
  float* out = (float*)d_out;

  char* wsb = (char*)d_ws;
  size_t off = 0;
  auto alloc = [&](size_t sz)->char*{
    char* p = wsb + off; off = (off + sz + 255) & ~(size_t)255; return p;
  };
  u16*   BE    = (u16*)  alloc((size_t)NE*HD*2);
  u16*   Hh    = (u16*)  alloc((size_t)NE*HD*2);
  float* score = (float*)alloc((size_t)NE*4);
  u16*   P     = (u16*)  alloc((size_t)NN*HD*2);
  u16*   Q     = (u16*)  alloc((size_t)NN*HD*2);
  float* bv    = (float*)alloc((size_t)NN*HD*4);
  u16*   bvb   = (u16*)  alloc((size_t)NN*HD*2);
  int*   offs  = (int*)  alloc((size_t)(NN+1)*4);
  int*   cur   = (int*)  alloc((size_t)NN*4);
  int*   eids  = (int*)  alloc((size_t)NE*4);
  float* flags = (float*)alloc((size_t)NN*8);
  u16*   eaw1f = (u16*)  alloc((size_t)65536*2);
  u16*   w1af  = (u16*)  alloc((size_t)65536*2);
  u16*   w1bf  = (u16*)  alloc((size_t)65536*2);
  u16*   w1cf  = (u16*)  alloc((size_t)65536*2);
  u16*   euw2f = (u16*)  alloc((size_t)65536*2);
  float* gG    = (float*)alloc((size_t)NG*768*4);
  float* logits= (float*)alloc((size_t)NG*4);

  // one-time per launch: weight repacks + b_e init + flags + CSR
  repack_k<<<32,256,0,stream>>>(ea_w1, eaw1f);
  repack_k<<<32,256,0,stream>>>(eu_w1, w1af);              // rows 0..255   (src b_v part)
  repack_k<<<32,256,0,stream>>>(eu_w1 + 258*HD, w1bf);     // rows 258..513 (recv b_v part)
  repack_k<<<32,256,0,stream>>>(eu_w1 + 516*HD, w1cf);     // rows 516..771 (b_e part)
  repack_k<<<32,256,0,stream>>>(eu_w2, euw2f);
  initbe_k<<<NE*64/256,256,0,stream>>>(ef, gall, BE);
  flags_k<<<NN/256,256,0,stream>>>(batch, heads, tails, flags);
  scan_k<<<1,256,0,stream>>>(ndeg, offs, cur);
  fill_k<<<NE/256,256,0,stream>>>(recvI, cur, eids);

  const int GRID_E = NE/64;   // 4096
  const int GRID_N = NN/64;   // 256

  for (int it=0; it<3; ++it){
    // score = sigmoid(relu(b_e@ea_w1+b1)@ea_w2+b2), second layer fused in-register
    gemm_k<MODE_SCORE><<<GRID_E,256,0,stream>>>(BE, eaw1f, score, nullptr,
        ea_b1, ea_w2, ea_b2, nullptr, nullptr, nullptr, nullptr, nullptr, nullptr);
    // scatter-softmax + degree-normalized aggregation -> b_v (f32 + bf16)
    agg_k<<<NN/4,256,0,stream>>>(score, BE, offs, eids, bv, bvb);
    // P = r_v@W1a + b1 ; Q = r_v@W1b  (head/tail rank-1 rows in epilogue)
    gemm_k<MODE_PQ><<<GRID_N,256,0,stream>>>(bvb, w1af, nullptr, P,
        eu_b1, nullptr, nullptr, nullptr, nullptr, nullptr, nullptr, flags, eu_w1 + 256*HD);
    gemm_k<MODE_PQ><<<GRID_N,256,0,stream>>>(bvb, w1bf, nullptr, Q,
        nullptr, nullptr, nullptr, nullptr, nullptr, nullptr, nullptr, flags, eu_w1 + 514*HD);
    // h = relu(b_e@W1c + P[src] + Q[recv])
    gemm_k<MODE_PRE><<<GRID_E,256,0,stream>>>(BE, w1cf, nullptr, Hh,
        nullptr, nullptr, nullptr, P, Q, srcI, recvI, nullptr, nullptr);
    if (it < 2){
      // b_e = h@eu_w2 + b2
      gemm_k<MODE_OUT><<<GRID_E,256,0,stream>>>(Hh, euw2f, nullptr, BE,
          eu_b2, nullptr, nullptr, nullptr, nullptr, nullptr, nullptr, nullptr, nullptr);
    } else {
      // final iter: fuse w_e = sigmoid((h@eu_w2+b2)@ew_w+ew_b); b_e never stored
      gemm_k<MODE_OUT_WE><<<GRID_E,256,0,stream>>>(Hh, euw2f, out, nullptr,
          eu_b2, ew_w, ew_b, nullptr, nullptr, nullptr, nullptr, nullptr, nullptr);
    }
  }

  // graph head (f32 exact, tiny; un-permutes positions)
  gmax_k<<<NG,256,0,stream>>>(bv, heads, tails, gG);
  glog_k<<<NG,256,0,stream>>>(gG, gw_w1, gw_b1, gw_w2, gw_b2, logits);
  gfin_k<<<1,256,0,stream>>>(gG, logits, out + NE);
}

// Round 5
// 1263.847 us; speedup vs baseline: 1.4789x; 1.0175x over previous
//
#include <hip/hip_runtime.h>
#include <stdint.h>

typedef unsigned short u16;
typedef unsigned int   u32;

#define NN 16384   // nodes
#define NE 262144  // edges
#define NG 64      // graphs
#define HD 256     // hidden

typedef __attribute__((ext_vector_type(8))) short bfrag;  // 8 bf16 (4 VGPR)
typedef __attribute__((ext_vector_type(4))) float ffrag;  // 4 f32 acc

__device__ __forceinline__ float bf2f(u16 h){
  union { u32 u; float f; } v; v.u = ((u32)h) << 16; return v.f;
}
__device__ __forceinline__ u16 f2bf(float x){
  union { float f; u32 u; } v; v.f = x;
  u32 r = v.u + 0x7fffu + ((v.u >> 16) & 1u);
  return (u16)(r >> 16);
}
__device__ __forceinline__ float sigmoidf(float x){ return 1.f/(1.f+__expf(-x)); }

// async global->LDS DMA, 16B per lane: lane i lands at (uniform lds base) + i*16
__device__ __forceinline__ void dma16(const void* g, void* l){
  __builtin_amdgcn_global_load_lds(
      (const __attribute__((address_space(1))) u32*)g,
      (__attribute__((address_space(3))) u32*)l, 16, 0, 0);
}

// Feature permutation pi: feature f lives at position p(f) = (f>>6)*64 + (f&15)*4
// + ((f>>4)&3); inv(p) = (p>>6)*64 + (p&3)*16 + ((p>>2)&15). Weights repacked with
// K-rows permuted by inv() so GEMMs contract correctly. Payoff: epilogues write
// packed uint2 and P/Q gathers are one uint2 per row.
// A staging (frag-ordered): wave w stages its 16 rows as [chunk q][row ml][8];
// lane l=(q*16+ml) carries row (l&15), k-chunk (l>>4). Reads are then the
// canonical lane-contiguous ds_read_b128 at (block*512 + l*8) — conflict-free.

enum { MODE_SCORE=0, MODE_PQ=4 };

template<int MODE>
__global__ __launch_bounds__(256, 3)
void gemm_k(const u16* __restrict__ A, const u16* __restrict__ Bf,
            float* __restrict__ outF, u16* __restrict__ outB,
            const float* __restrict__ bias, const float* __restrict__ vec,
            const float* __restrict__ scal,
            const float* __restrict__ flags, const float* __restrict__ ht)
{
  __shared__ __align__(16) u16 sA[4*512];     // 4KB: [mtblock][l][8]
  __shared__ __align__(16) u16 sB[16*64*8];   // 16KB
  __shared__ float sred[4][64];

  const int l  = threadIdx.x & 63;
  const int w  = threadIdx.x >> 6;
  const int q  = l >> 4;
  const int ml = l & 15;
  const long rowBase = (long)blockIdx.x * 64;

  const u16* gA = A + (size_t)(rowBase + w*16 + (l & 15))*HD + (l >> 4)*8;
  u16* lA = sA + w*512;
  const u16* gB = Bf + (size_t)l*8;

  ffrag acc[4][4];
#pragma unroll
  for (int mt=0; mt<4; ++mt)
#pragma unroll
    for (int n=0; n<4; ++n) acc[mt][n] = (ffrag){0.f,0.f,0.f,0.f};

#pragma unroll 1
  for (int c=0; c<8; ++c){
    dma16(gA + c*32, lA);
#pragma unroll
    for (int t=0; t<4; ++t)
      dma16(gB + ((size_t)c*16 + w*4 + t)*512, sB + (w*4+t)*512);
    __syncthreads();
    bfrag a[4], b[4];
#pragma unroll
    for (int mt=0; mt<4; ++mt) a[mt] = *(const bfrag*)(sA + mt*512 + l*8);
#pragma unroll
    for (int n=0; n<4; ++n)    b[n]  = *(const bfrag*)(sB + (w*4+n)*512 + l*8);
#pragma unroll
    for (int mt=0; mt<4; ++mt)
#pragma unroll
      for (int n=0; n<4; ++n)
        acc[mt][n] = __builtin_amdgcn_mfma_f32_16x16x32_bf16(a[mt], b[n], acc[mt][n], 0, 0, 0);
    __syncthreads();
  }

  if constexpr (MODE==MODE_SCORE){
    float part[4][4];
#pragma unroll
    for (int mt=0; mt<4; ++mt)
#pragma unroll
      for (int r=0; r<4; ++r) part[mt][r] = 0.f;
#pragma unroll
    for (int n=0; n<4; ++n){
      const int col = (w*4+n)*16+ml;
      const float bb = bias[col], vvn = vec[col];
#pragma unroll
      for (int mt=0; mt<4; ++mt)
#pragma unroll
        for (int r=0; r<4; ++r)
          part[mt][r] += fmaxf(acc[mt][n][r] + bb, 0.f) * vvn;
    }
#pragma unroll
    for (int mt=0; mt<4; ++mt)
#pragma unroll
      for (int r=0; r<4; ++r){
        float p = part[mt][r];
        p += __shfl_xor(p, 1, 64); p += __shfl_xor(p, 2, 64);
        p += __shfl_xor(p, 4, 64); p += __shfl_xor(p, 8, 64);
        part[mt][r] = p;
      }
    if (ml == 0)
#pragma unroll
      for (int mt=0; mt<4; ++mt)
#pragma unroll
        for (int r=0; r<4; ++r)
          sred[w][mt*16 + q*4 + r] = part[mt][r];
    __syncthreads();
    if (threadIdx.x < 64){
      const int t = threadIdx.x;
      float v = sred[0][t] + sred[1][t] + sred[2][t] + sred[3][t];
      outF[rowBase + t] = sigmoidf(v + scal[0]);
    }
  } else { // MODE_PQ: node GEMM + rank-1 head/tail rows (+optional bias)
#pragma unroll
    for (int mt=0; mt<4; ++mt)
#pragma unroll
      for (int r=0; r<4; ++r){
        long row = rowBase + mt*16 + q*4 + r;
        const float fh = flags[2*row];
        const float ft = flags[2*row+1];
        u16 o[4];
#pragma unroll
        for (int n=0; n<4; ++n){
          const int col = (w*4+n)*16+ml;
          float v = acc[mt][n][r] + fh*ht[col] + ft*ht[HD+col];
          if (bias) v += bias[col];
          o[n] = f2bf(v);
        }
        uint2 pk; pk.x = (u32)o[0] | ((u32)o[1]<<16); pk.y = (u32)o[2] | ((u32)o[3]<<16);
        *(uint2*)(outB + (size_t)row*HD + w*64 + ml*4) = pk;
      }
  }
}

// ---- MEGA: per-iteration fused edge pipeline ----
// GEMM1: h = relu(BE@W1c + P[src] + Q[recv])       (b1 folded into P)
// GEMM2: b_e' = h@W2 + b2
// !LAST: write BE' (in-place safe: block only touches its own rows),
//        GEMM3: score' = sigmoid(relu(b_e'@ea_w1+ea_b1)@ea_w2+ea_b2)
// LAST:  w_e = sigmoid(b_e'@ew_w + ew_b) -> out     (b_e never hits HBM)
// h / b_e' tiles round-trip through sH in A-fragment layout.
template<bool LAST>
__global__ __launch_bounds__(256, 3)
void mega_k(u16* __restrict__ BE, const u16* __restrict__ w1cf,
            const u16* __restrict__ w2f, const u16* __restrict__ eaw1f,
            float* __restrict__ scoreOut, float* __restrict__ weOut,
            const u16* __restrict__ Pg, const u16* __restrict__ Qg,
            const int* __restrict__ srcI, const int* __restrict__ recvI,
            const float* __restrict__ b2,
            const float* __restrict__ sb1, const float* __restrict__ sv,
            const float* __restrict__ ssc,
            const float* __restrict__ wv, const float* __restrict__ wb)
{
  __shared__ __align__(16) u16 sA[4*512];      // 4KB  A staging (per K-step)
  __shared__ __align__(16) u16 sB[16*64*8];    // 16KB B staging (per K-step)
  __shared__ __align__(16) u16 sH[8*4*64*8];   // 32KB h / b_e' in frag layout
  __shared__ float sred[4][64];                // 1KB  col-band reduce

  const int l  = threadIdx.x & 63;
  const int w  = threadIdx.x >> 6;
  const int q  = l >> 4;
  const int ml = l & 15;
  const long rowBase = (long)blockIdx.x * 64;

  const u16* gA = BE + (size_t)(rowBase + w*16 + (l & 15))*HD + (l >> 4)*8;
  u16* lA = sA + w*512;
  const u16* gB1 = w1cf  + (size_t)l*8;
  const u16* gB2 = w2f   + (size_t)l*8;
  const u16* gB3 = eaw1f + (size_t)l*8;

  // sH write address pieces (value at local row mt*16+q*4+r, position p=w*64+ml*4+n):
  // chunk c'=w*2+(ml>>3); q'=(ml&7)>>1; j=(ml&1)*4+n; dest ml'=q*4+r.
  const int hc = w*2 + (ml>>3);
  const int hq = (ml&7)>>1;
  const int hj = (ml&1)*4;

  ffrag acc[4][4];
#pragma unroll
  for (int mt=0; mt<4; ++mt)
#pragma unroll
    for (int n=0; n<4; ++n) acc[mt][n] = (ffrag){0.f,0.f,0.f,0.f};

  // ---------- GEMM1 ----------
#pragma unroll 1
  for (int c=0; c<8; ++c){
    dma16(gA + c*32, lA);
#pragma unroll
    for (int t=0; t<4; ++t)
      dma16(gB1 + ((size_t)c*16 + w*4 + t)*512, sB + (w*4+t)*512);
    __syncthreads();
    bfrag a[4], b[4];
#pragma unroll
    for (int mt=0; mt<4; ++mt) a[mt] = *(const bfrag*)(sA + mt*512 + l*8);
#pragma unroll
    for (int n=0; n<4; ++n)    b[n]  = *(const bfrag*)(sB + (w*4+n)*512 + l*8);
#pragma unroll
    for (int mt=0; mt<4; ++mt)
#pragma unroll
      for (int n=0; n<4; ++n)
        acc[mt][n] = __builtin_amdgcn_mfma_f32_16x16x32_bf16(a[mt], b[n], acc[mt][n], 0, 0, 0);
    __syncthreads();
  }
  // epilogue 1: h -> sH (frag layout)
#pragma unroll
  for (int mt=0; mt<4; ++mt)
#pragma unroll
    for (int r=0; r<4; ++r){
      long row = rowBase + mt*16 + q*4 + r;
      const int si = srcI[row];
      const int ri = recvI[row];
      uint2 pu = *(const uint2*)(Pg + (size_t)si*HD + w*64 + ml*4);
      uint2 qu = *(const uint2*)(Qg + (size_t)ri*HD + w*64 + ml*4);
      float pv[4] = { bf2f((u16)(pu.x & 0xffff)), bf2f((u16)(pu.x >> 16)),
                      bf2f((u16)(pu.y & 0xffff)), bf2f((u16)(pu.y >> 16)) };
      float qv[4] = { bf2f((u16)(qu.x & 0xffff)), bf2f((u16)(qu.x >> 16)),
                      bf2f((u16)(qu.y & 0xffff)), bf2f((u16)(qu.y >> 16)) };
      u16 o[4];
#pragma unroll
      for (int n=0; n<4; ++n)
        o[n] = f2bf(fmaxf(acc[mt][n][r] + pv[n] + qv[n], 0.f));
      uint2 pk; pk.x = (u32)o[0] | ((u32)o[1]<<16); pk.y = (u32)o[2] | ((u32)o[3]<<16);
      *(uint2*)(sH + ((hc*4 + mt)*64 + hq*16 + q*4 + r)*8 + hj) = pk;
    }

  // ---------- GEMM2 ----------
#pragma unroll
  for (int mt=0; mt<4; ++mt)
#pragma unroll
    for (int n=0; n<4; ++n) acc[mt][n] = (ffrag){0.f,0.f,0.f,0.f};
#pragma unroll 1
  for (int c=0; c<8; ++c){
#pragma unroll
    for (int t=0; t<4; ++t)
      dma16(gB2 + ((size_t)c*16 + w*4 + t)*512, sB + (w*4+t)*512);
    __syncthreads();   // also guards sH writes before first read
    bfrag a[4], b[4];
#pragma unroll
    for (int mt=0; mt<4; ++mt) a[mt] = *(const bfrag*)(sH + ((c*4+mt)*64 + l)*8);
#pragma unroll
    for (int n=0; n<4; ++n)    b[n]  = *(const bfrag*)(sB + (w*4+n)*512 + l*8);
#pragma unroll
    for (int mt=0; mt<4; ++mt)
#pragma unroll
      for (int n=0; n<4; ++n)
        acc[mt][n] = __builtin_amdgcn_mfma_f32_16x16x32_bf16(a[mt], b[n], acc[mt][n], 0, 0, 0);
    __syncthreads();
  }

  float bia2[4];
#pragma unroll
  for (int n=0; n<4; ++n) bia2[n] = b2[(w*4+n)*16+ml];

  if constexpr (!LAST){
    // epilogue 2: b_e' -> global BE (in-place) + sH for GEMM3
#pragma unroll
    for (int mt=0; mt<4; ++mt)
#pragma unroll
      for (int r=0; r<4; ++r){
        long row = rowBase + mt*16 + q*4 + r;
        u16 o[4];
#pragma unroll
        for (int n=0; n<4; ++n) o[n] = f2bf(acc[mt][n][r] + bia2[n]);
        uint2 pk; pk.x = (u32)o[0] | ((u32)o[1]<<16); pk.y = (u32)o[2] | ((u32)o[3]<<16);
        *(uint2*)(BE + (size_t)row*HD + w*64 + ml*4) = pk;
        *(uint2*)(sH + ((hc*4 + mt)*64 + hq*16 + q*4 + r)*8 + hj) = pk;
      }
    // ---------- GEMM3 (score) ----------
#pragma unroll
    for (int mt=0; mt<4; ++mt)
#pragma unroll
      for (int n=0; n<4; ++n) acc[mt][n] = (ffrag){0.f,0.f,0.f,0.f};
#pragma unroll 1
    for (int c=0; c<8; ++c){
#pragma unroll
      for (int t=0; t<4; ++t)
        dma16(gB3 + ((size_t)c*16 + w*4 + t)*512, sB + (w*4+t)*512);
      __syncthreads();
      bfrag a[4], b[4];
#pragma unroll
      for (int mt=0; mt<4; ++mt) a[mt] = *(const bfrag*)(sH + ((c*4+mt)*64 + l)*8);
#pragma unroll
      for (int n=0; n<4; ++n)    b[n]  = *(const bfrag*)(sB + (w*4+n)*512 + l*8);
#pragma unroll
      for (int mt=0; mt<4; ++mt)
#pragma unroll
        for (int n=0; n<4; ++n)
          acc[mt][n] = __builtin_amdgcn_mfma_f32_16x16x32_bf16(a[mt], b[n], acc[mt][n], 0, 0, 0);
      __syncthreads();
    }
    float part[4][4];
#pragma unroll
    for (int mt=0; mt<4; ++mt)
#pragma unroll
      for (int r=0; r<4; ++r) part[mt][r] = 0.f;
#pragma unroll
    for (int n=0; n<4; ++n){
      const int col = (w*4+n)*16+ml;
      const float bb = sb1[col], vvn = sv[col];
#pragma unroll
      for (int mt=0; mt<4; ++mt)
#pragma unroll
        for (int r=0; r<4; ++r)
          part[mt][r] += fmaxf(acc[mt][n][r] + bb, 0.f) * vvn;
    }
#pragma unroll
    for (int mt=0; mt<4; ++mt)
#pragma unroll
      for (int r=0; r<4; ++r){
        float p = part[mt][r];
        p += __shfl_xor(p, 1, 64); p += __shfl_xor(p, 2, 64);
        p += __shfl_xor(p, 4, 64); p += __shfl_xor(p, 8, 64);
        part[mt][r] = p;
      }
    if (ml == 0)
#pragma unroll
      for (int mt=0; mt<4; ++mt)
#pragma unroll
        for (int r=0; r<4; ++r)
          sred[w][mt*16 + q*4 + r] = part[mt][r];
    __syncthreads();
    if (threadIdx.x < 64){
      const int t = threadIdx.x;
      float v = sred[0][t] + sred[1][t] + sred[2][t] + sred[3][t];
      scoreOut[rowBase + t] = sigmoidf(v + ssc[0]);
    }
  } else {
    // epilogue 2 (last iter): w_e = sigmoid(b_e'. ew_w + ew_b) directly
    float part[4][4];
#pragma unroll
    for (int mt=0; mt<4; ++mt)
#pragma unroll
      for (int r=0; r<4; ++r) part[mt][r] = 0.f;
#pragma unroll
    for (int n=0; n<4; ++n){
      const float vvn = wv[(w*4+n)*16+ml];
#pragma unroll
      for (int mt=0; mt<4; ++mt)
#pragma unroll
        for (int r=0; r<4; ++r)
          part[mt][r] += (acc[mt][n][r] + bia2[n]) * vvn;
    }
#pragma unroll
    for (int mt=0; mt<4; ++mt)
#pragma unroll
      for (int r=0; r<4; ++r){
        float p = part[mt][r];
        p += __shfl_xor(p, 1, 64); p += __shfl_xor(p, 2, 64);
        p += __shfl_xor(p, 4, 64); p += __shfl_xor(p, 8, 64);
        part[mt][r] = p;
      }
    if (ml == 0)
#pragma unroll
      for (int mt=0; mt<4; ++mt)
#pragma unroll
        for (int r=0; r<4; ++r)
          sred[w][mt*16 + q*4 + r] = part[mt][r];
    __syncthreads();
    if (threadIdx.x < 64){
      const int t = threadIdx.x;
      float v = sred[0][t] + sred[1][t] + sred[2][t] + sred[3][t];
      weOut[rowBase + t] = sigmoidf(v + wb[0]);
    }
  }
}

// repack B[256 x 256] f32 row-major -> bf16 frag layout [c][n][lane][8],
// K-rows permuted: packed row kp takes source feature inv(kp).
__global__ void repack_k(const float* __restrict__ B, u16* __restrict__ out){
  int t = blockIdx.x*256 + threadIdx.x;        // 8192 total
  int l = t & 63, n = (t>>6)&15, c = t>>10;
  int col = n*16 + (l&15);
  int kbase = c*32 + ((l>>4)<<3);
#pragma unroll
  for (int j=0; j<8; ++j){
    int kp = kbase + j;
    int f = (kp>>6)*64 + (kp&3)*16 + ((kp>>2)&15);   // inv(kp)
    out[(size_t)t*8 + j] = f2bf(B[(size_t)f*HD + col]);
  }
}

// b_e(iter0) = [edge_features | g_all] -> bf16, position-permuted layout
__global__ void initbe_k(const float* __restrict__ ef, const float* __restrict__ gall,
                         u16* __restrict__ BE){
  int t = blockIdx.x*256 + threadIdx.x;        // NE*64
  int e = t >> 6; int p4 = (t & 63) * 4;
  int w64 = p4 >> 6, mlr = (p4 >> 2) & 15;
  u16 o[4];
#pragma unroll
  for (int i=0; i<4; ++i){
    int f = w64*64 + i*16 + mlr;                 // inv(p4+i)
    float v = (f < 192) ? ef[(size_t)e*192 + f] : gall[f - 192];
    o[i] = f2bf(v);
  }
  uint2 pk; pk.x = (u32)o[0] | ((u32)o[1]<<16); pk.y = (u32)o[2] | ((u32)o[3]<<16);
  *(uint2*)(BE + (size_t)e*HD + p4) = pk;
}

__global__ void flags_k(const int* __restrict__ batch, const int* __restrict__ heads,
                        const int* __restrict__ tails, float* __restrict__ flags){
  int n = blockIdx.x*256 + threadIdx.x;
  int g = batch[n];
  flags[2*n]   = (n == heads[g]) ? 1.f : 0.f;
  flags[2*n+1] = (n == tails[g]) ? 1.f : 0.f;
}

// exclusive prefix sum of degrees -> CSR offsets (+ cursor copy), single block
__global__ void scan_k(const int* __restrict__ deg, int* __restrict__ offs,
                       int* __restrict__ cur){
  __shared__ int part[256];
  int tid = threadIdx.x;
  int base = tid * 64;
  int s = 0;
  for (int j=0; j<64; ++j) s += deg[base+j];
  part[tid] = s;
  __syncthreads();
  if (tid == 0){
    int run = 0;
    for (int i=0; i<256; ++i){ int t = part[i]; part[i] = run; run += t; }
  }
  __syncthreads();
  int run = part[tid];
  for (int j=0; j<64; ++j){
    offs[base+j] = run; cur[base+j] = run; run += deg[base+j];
  }
  if (tid == 255) offs[NN] = run;
}

__global__ void fill_k(const int* __restrict__ recv, int* __restrict__ cur,
                       int* __restrict__ eids){
  int e = blockIdx.x*256 + threadIdx.x;
  int r = recv[e];
  int p = atomicAdd(&cur[r], 1);
  eids[p] = e;
}

// per-node softmax over incoming edges + weighted aggregation, one wave per node
__global__ __launch_bounds__(256)
void agg_k(const float* __restrict__ score, const u16* __restrict__ BE,
           const int* __restrict__ offs, const int* __restrict__ eids,
           float* __restrict__ bv, u16* __restrict__ bvb){
  int node = blockIdx.x*4 + (threadIdx.x >> 6);
  int l = threadIdx.x & 63;
  int beg = offs[node], end = offs[node+1];

  float m = -1e30f;
  for (int i=beg+l; i<end; i+=64) m = fmaxf(m, score[eids[i]]);
#pragma unroll
  for (int d=1; d<64; d<<=1) m = fmaxf(m, __shfl_xor(m, d, 64));

  float s = 0.f;
  for (int i=beg+l; i<end; i+=64) s += __expf(score[eids[i]] - m);
#pragma unroll
  for (int d=1; d<64; d<<=1) s += __shfl_xor(s, d, 64);

  float deg = (float)(end - beg);
  float scale = (end > beg) ? (1.f/s) * (1.f/(1.f+deg)) : 0.f;

  float a0=0.f, a1=0.f, a2=0.f, a3=0.f;
  for (int i=beg; i<end; ++i){
    int e = eids[i];
    float al = __expf(score[e] - m);
    uint2 uv = *(const uint2*)(BE + (size_t)e*HD + l*4);
    a0 += al * bf2f((u16)(uv.x & 0xffff));
    a1 += al * bf2f((u16)(uv.x >> 16));
    a2 += al * bf2f((u16)(uv.y & 0xffff));
    a3 += al * bf2f((u16)(uv.y >> 16));
  }
  size_t o = (size_t)node*HD + l*4;
  a0 *= scale; a1 *= scale; a2 *= scale; a3 *= scale;
  bv[o+0]=a0; bv[o+1]=a1; bv[o+2]=a2; bv[o+3]=a3;
  uint2 p; p.x = (u32)f2bf(a0) | ((u32)f2bf(a1)<<16);
  p.y = (u32)f2bf(a2) | ((u32)f2bf(a3)<<16);
  *(uint2*)(bvb + o) = p;
}

// graph head: g_max + gather head/tail rows -> g_G [64][768] f32 (position space)
__global__ void gmax_k(const float* __restrict__ bv, const int* __restrict__ heads,
                       const int* __restrict__ tails, float* __restrict__ gG){
  int g = blockIdx.x, col = threadIdx.x;
  float mx = -1e30f;
  const float* p = bv + (size_t)g*256*HD + col;
  for (int i=0; i<256; ++i) mx = fmaxf(mx, p[(size_t)i*HD]);
  gG[g*768 + col]       = mx;
  gG[g*768 + 256 + col] = bv[(size_t)heads[g]*HD + col];
  gG[g*768 + 512 + col] = bv[(size_t)tails[g]*HD + col];
}

__global__ void glog_k(const float* __restrict__ gG, const float* __restrict__ w1,
                       const float* __restrict__ b1, const float* __restrict__ w2,
                       const float* __restrict__ b2, float* __restrict__ logits){
  int g = blockIdx.x, n = threadIdx.x;
  float a = b1[n];
  const float* gg = gG + g*768;
  for (int k=0; k<768; ++k){
    int b = k >> 8, p = k & 255;
    int f = (p>>6)*64 + (p&3)*16 + ((p>>2)&15);   // inv(p)
    a += gg[k] * w1[(size_t)(b*256 + f)*HD + n];
  }
  a = fmaxf(a, 0.f) * w2[n];
#pragma unroll
  for (int d=1; d<64; d<<=1) a += __shfl_xor(a, d, 64);
  __shared__ float red[4];
  if ((threadIdx.x & 63) == 0) red[threadIdx.x >> 6] = a;
  __syncthreads();
  if (threadIdx.x == 0) logits[g] = red[0]+red[1]+red[2]+red[3] + b2[0];
}

__global__ void gfin_k(const float* __restrict__ gG, const float* __restrict__ logits,
                       float* __restrict__ out){
  int tid = threadIdx.x;
  float m = -1e30f;
  for (int g=0; g<NG; ++g) m = fmaxf(m, logits[g]);
  float s = 0.f;
  for (int g=0; g<NG; ++g) s += __expf(logits[g] - m);
  float inv = 1.f/s;
  for (int j=tid; j<768; j+=256){
    int b = j >> 8, f = j & 255;
    int p = (f>>6)*64 + (f&15)*4 + ((f>>4)&3);    // pi(f): un-permute for output
    float o = 0.f;
    for (int g=0; g<NG; ++g) o += __expf(logits[g]-m)*inv * gG[g*768 + b*256 + p];
    out[j] = o;
  }
}

extern "C" void kernel_launch(void* const* d_in, const int* in_sizes, int n_in,
                              void* d_out, int out_size, void* d_ws, size_t ws_size,
                              hipStream_t stream)
{
  const float* ef    = (const float*)d_in[0];
  const float* gall  = (const float*)d_in[1];
  const float* ea_w1 = (const float*)d_in[2];
  const float* ea_b1 = (const float*)d_in[3];
  const float* ea_w2 = (const float*)d_in[4];
  const float* ea_b2 = (const float*)d_in[5];
  const float* eu_w1 = (const float*)d_in[6];
  const float* eu_b1 = (const float*)d_in[7];
  const float* eu_w2 = (const float*)d_in[8];
  const float* eu_b2 = (const float*)d_in[9];
  const float* gw_w1 = (const float*)d_in[10];
  const float* gw_b1 = (const float*)d_in[11];
  const float* gw_w2 = (const float*)d_in[12];
  const float* gw_b2 = (const float*)d_in[13];
  const float* ew_w  = (const float*)d_in[14];
  const float* ew_b  = (const float*)d_in[15];
  const int* eidx    = (const int*)d_in[16];
  const int* srcI    = eidx;
  const int* recvI   = eidx + NE;
  const int* ndeg    = (const int*)d_in[17];
  const int* batch   = (const int*)d_in[18];
  const int* heads   = (const int*)d_in[19];
  const int* tails   = (const int*)d_in[20];
  float* out = (float*)d_out;

  char* wsb = (char*)d_ws;
  size_t off = 0;
  auto alloc = [&](size_t sz)->char*{
    char* p = wsb + off; off = (off + sz + 255) & ~(size_t)255; return p;
  };
  u16*   BE    = (u16*)  alloc((size_t)NE*HD*2);
  float* score = (float*)alloc((size_t)NE*4);
  u16*   P     = (u16*)  alloc((size_t)NN*HD*2);
  u16*   Q     = (u16*)  alloc((size_t)NN*HD*2);
  float* bv    = (float*)alloc((size_t)NN*HD*4);
  u16*   bvb   = (u16*)  alloc((size_t)NN*HD*2);
  int*   offs  = (int*)  alloc((size_t)(NN+1)*4);
  int*   cur   = (int*)  alloc((size_t)NN*4);
  int*   eids  = (int*)  alloc((size_t)NE*4);
  float* flags = (float*)alloc((size_t)NN*8);
  u16*   eaw1f = (u16*)  alloc((size_t)65536*2);
  u16*   w1af  = (u16*)  alloc((size_t)65536*2);
  u16*   w1bf  = (u16*)  alloc((size_t)65536*2);
  u16*   w1cf  = (u16*)  alloc((size_t)65536*2);
  u16*   euw2f = (u16*)  alloc((size_t)65536*2);
  float* gG    = (float*)alloc((size_t)NG*768*4);
  float* logits= (float*)alloc((size_t)NG*4);

  // one-time per launch: weight repacks + b_e init + flags + CSR
  repack_k<<<32,256,0,stream>>>(ea_w1, eaw1f);
  repack_k<<<32,256,0,stream>>>(eu_w1, w1af);              // rows 0..255   (src b_v part)
  repack_k<<<32,256,0,stream>>>(eu_w1 + 258*HD, w1bf);     // rows 258..513 (recv b_v part)
  repack_k<<<32,256,0,stream>>>(eu_w1 + 516*HD, w1cf);     // rows 516..771 (b_e part)
  repack_k<<<32,256,0,stream>>>(eu_w2, euw2f);
  initbe_k<<<NE*64/256,256,0,stream>>>(ef, gall, BE);
  flags_k<<<NN/256,256,0,stream>>>(batch, heads, tails, flags);
  scan_k<<<1,256,0,stream>>>(ndeg, offs, cur);
  fill_k<<<NE/256,256,0,stream>>>(recvI, cur, eids);

  // score for iter0 (reads the freshly-built BE)
  gemm_k<MODE_SCORE><<<NE/64,256,0,stream>>>(BE, eaw1f, score, nullptr,
      ea_b1, ea_w2, ea_b2, nullptr, nullptr);

  for (int it=0; it<3; ++it){
    // scatter-softmax + degree-normalized aggregation -> b_v (f32 + bf16)
    agg_k<<<NN/4,256,0,stream>>>(score, BE, offs, eids, bv, bvb);
    // P = r_v@W1a + b1 ; Q = r_v@W1b  (head/tail rank-1 rows in epilogue)
    gemm_k<MODE_PQ><<<NN/64,256,0,stream>>>(bvb, w1af, nullptr, P,
        eu_b1, nullptr, nullptr, flags, eu_w1 + 256*HD);
    gemm_k<MODE_PQ><<<NN/64,256,0,stream>>>(bvb, w1bf, nullptr, Q,
        nullptr, nullptr, nullptr, flags, eu_w1 + 514*HD);
    // fused edge update (+ next score, or final w_e)
    if (it < 2){
      mega_k<false><<<NE/64,256,0,stream>>>(BE, w1cf, euw2f, eaw1f,
          score, nullptr, P, Q, srcI, recvI, eu_b2,
          ea_b1, ea_w2, ea_b2, nullptr, nullptr);
    } else {
      mega_k<true><<<NE/64,256,0,stream>>>(BE, w1cf, euw2f, eaw1f,
          nullptr, out, P, Q, srcI, recvI, eu_b2,
          nullptr, nullptr, nullptr, ew_w, ew_b);
    }
  }

  // graph head (f32 exact, tiny; un-permutes positions)
  gmax_k<<<NG,256,0,stream>>>(bv, heads, tails, gG);
  glog_k<<<NG,256,0,stream>>>(gG, gw_w1, gw_b1, gw_w2, gw_b2, logits);
  gfin_k<<<1,256,0,stream>>>(gG, logits, out + NE);
}

// Round 6
// 1095.327 us; speedup vs baseline: 1.7065x; 1.1539x over previous
//
#include <hip/hip_runtime.h>
#include <stdint.h>

typedef unsigned short u16;
typedef unsigned int   u32;

#define NN 16384   // nodes
#define NE 262144  // edges
#define NG 64      // graphs
#define HD 256     // hidden
#define SHS 264    // row-major LDS tile stride in u16 (+8 pad -> 2-way-free banks)

typedef __attribute__((ext_vector_type(8))) short bfrag;  // 8 bf16 (4 VGPR)
typedef __attribute__((ext_vector_type(4))) float ffrag;  // 4 f32 acc

__device__ __forceinline__ float bf2f(u16 h){
  union { u32 u; float f; } v; v.u = ((u32)h) << 16; return v.f;
}
__device__ __forceinline__ u16 f2bf(float x){
  union { float f; u32 u; } v; v.f = x;
  u32 r = v.u + 0x7fffu + ((v.u >> 16) & 1u);
  return (u16)(r >> 16);
}
__device__ __forceinline__ float sigmoidf(float x){ return 1.f/(1.f+__expf(-x)); }

// async global->LDS DMA, 16B/lane: lane i lands at (wave-uniform base) + i*16
__device__ __forceinline__ void dma16(const void* g, void* l){
  __builtin_amdgcn_global_load_lds(
      (const __attribute__((address_space(1))) u32*)g,
      (__attribute__((address_space(3))) u32*)l, 16, 0, 0);
}

// Feature permutation pi: feature f lives at position p(f)=(f>>6)*64+(f&15)*4
// +((f>>4)&3); inv(p)=(p>>6)*64+(p&3)*16+((p>>2)&15). Weights repacked with
// K-rows permuted by inv(). Epilogues write packed uint2; P/Q gathers are one
// uint2 per row.
//
// R6 structure (attacks R5's measured LDS-BW + bank-conflict + barrier bound):
//  * B-fragments come straight from global (L2-resident 128KB weights) as
//    coalesced b128 -- no sB staging, no per-step barriers.
//  * Activation tile staged into LDS ONCE via dma16 (frag layout), K-loops
//    are barrier-free.
//  * mega's h / b_e' tiles live in ONE reused 33KB LDS buffer, row-major
//    stride SHS=264 u16: epilogue uint2 writes hit banks (16q+4r+2ml)%32
//    (2 accesses/bank = free) and A-frag b128 reads hit 4(ml+q)%32-style
//    patterns (2-way = free). R5's frag-layout scatter was ~8-way.

enum { MODE_SCORE=0, MODE_PQ=4 };

// SCORE: outF = sigmoid(relu(A@Bf0+bias)@vec + scal)  (per-row scalar)
// PQ (grid.y=0/1): out{0,1} = A@Bf{0,1} [+bias] + flag-rank1(ht{0,1})
template<int MODE>
__global__ __launch_bounds__(256, 3)
void gemm_k(const u16* __restrict__ A, const u16* __restrict__ Bf0,
            const u16* __restrict__ Bf1,
            float* __restrict__ outF, u16* __restrict__ out0, u16* __restrict__ out1,
            const float* __restrict__ bias, const float* __restrict__ vec,
            const float* __restrict__ scal, const float* __restrict__ flags,
            const float* __restrict__ ht0, const float* __restrict__ ht1)
{
  __shared__ __align__(16) u16 sA[16384];   // 32KB, frag layout [(c*4+mt)*512 + l*8]
  __shared__ float sred[4][64];

  const int l  = threadIdx.x & 63;
  const int w  = threadIdx.x >> 6;
  const int q  = l >> 4;
  const int ml = l & 15;
  const long rowBase = (long)blockIdx.x * 64;

  const u16* Bf   = Bf0;
  u16*       outB = out0;
  const float* htp = ht0;
  const float* bp  = bias;
  if (MODE==MODE_PQ && blockIdx.y){ Bf = Bf1; outB = out1; htp = ht1; bp = nullptr; }

  // stage A tile once (frag layout), then barrier-free K loop
  const u16* gA = A + (size_t)(rowBase + w*16 + ml)*HD + q*8;
#pragma unroll
  for (int c=0; c<8; ++c) dma16(gA + c*32, sA + (c*4+w)*512);
  __syncthreads();

  ffrag acc[4][4];
#pragma unroll
  for (int mt=0; mt<4; ++mt)
#pragma unroll
    for (int n=0; n<4; ++n) acc[mt][n] = (ffrag){0.f,0.f,0.f,0.f};

#pragma unroll 1
  for (int c=0; c<8; ++c){
    bfrag a[4], b[4];
#pragma unroll
    for (int n=0; n<4; ++n)
      b[n] = *(const bfrag*)(Bf + (((size_t)c*16 + w*4 + n)*64 + l)*8);
#pragma unroll
    for (int mt=0; mt<4; ++mt) a[mt] = *(const bfrag*)(sA + (c*4+mt)*512 + l*8);
#pragma unroll
    for (int mt=0; mt<4; ++mt)
#pragma unroll
      for (int n=0; n<4; ++n)
        acc[mt][n] = __builtin_amdgcn_mfma_f32_16x16x32_bf16(a[mt], b[n], acc[mt][n], 0, 0, 0);
  }

  if constexpr (MODE==MODE_SCORE){
    float part[4][4];
#pragma unroll
    for (int mt=0; mt<4; ++mt)
#pragma unroll
      for (int r=0; r<4; ++r) part[mt][r] = 0.f;
#pragma unroll
    for (int n=0; n<4; ++n){
      const int col = (w*4+n)*16+ml;
      const float bb = bias[col], vvn = vec[col];
#pragma unroll
      for (int mt=0; mt<4; ++mt)
#pragma unroll
        for (int r=0; r<4; ++r)
          part[mt][r] += fmaxf(acc[mt][n][r] + bb, 0.f) * vvn;
    }
#pragma unroll
    for (int mt=0; mt<4; ++mt)
#pragma unroll
      for (int r=0; r<4; ++r){
        float p = part[mt][r];
        p += __shfl_xor(p, 1, 64); p += __shfl_xor(p, 2, 64);
        p += __shfl_xor(p, 4, 64); p += __shfl_xor(p, 8, 64);
        part[mt][r] = p;
      }
    if (ml == 0)
#pragma unroll
      for (int mt=0; mt<4; ++mt)
#pragma unroll
        for (int r=0; r<4; ++r)
          sred[w][mt*16 + q*4 + r] = part[mt][r];
    __syncthreads();
    if (threadIdx.x < 64){
      const int t = threadIdx.x;
      float v = sred[0][t] + sred[1][t] + sred[2][t] + sred[3][t];
      outF[rowBase + t] = sigmoidf(v + scal[0]);
    }
  } else { // MODE_PQ
#pragma unroll
    for (int mt=0; mt<4; ++mt)
#pragma unroll
      for (int r=0; r<4; ++r){
        long row = rowBase + mt*16 + q*4 + r;
        const float fh = flags[2*row];
        const float ft = flags[2*row+1];
        u16 o[4];
#pragma unroll
        for (int n=0; n<4; ++n){
          const int col = (w*4+n)*16+ml;
          float v = acc[mt][n][r] + fh*htp[col] + ft*htp[HD+col];
          if (bp) v += bp[col];
          o[n] = f2bf(v);
        }
        uint2 pk; pk.x = (u32)o[0] | ((u32)o[1]<<16); pk.y = (u32)o[2] | ((u32)o[3]<<16);
        *(uint2*)(outB + (size_t)row*HD + w*64 + ml*4) = pk;
      }
  }
}

// ---- MEGA: per-iteration fused edge pipeline (3 chained GEMMs, one LDS tile) ----
// GEMM1: h = relu(BE@W1c + P[src]+Q[recv]); GEMM2: b_e' = h@W2 + b2;
// !LAST: BE'=b_e' to HBM, GEMM3: score' = sigmoid(relu(b_e'@ea_w1+b1)@ea_w2+b2)
// LAST:  w_e = sigmoid(b_e'@ew_w+ew_b) directly (b_e' never stored).
template<bool LAST>
__global__ __launch_bounds__(256, 3)
void mega_k(u16* __restrict__ BE, const u16* __restrict__ w1cf,
            const u16* __restrict__ w2f, const u16* __restrict__ eaw1f,
            float* __restrict__ scoreOut, float* __restrict__ weOut,
            const u16* __restrict__ Pg, const u16* __restrict__ Qg,
            const int* __restrict__ srcI, const int* __restrict__ recvI,
            const float* __restrict__ b2,
            const float* __restrict__ sb1, const float* __restrict__ sv,
            const float* __restrict__ ssc,
            const float* __restrict__ wv, const float* __restrict__ wb)
{
  // one buffer, two lifetimes: frag-layout staged BE (32KB), then row-major-264
  // h / b_e' (33792B). Transitions guarded by barriers.
  __shared__ __align__(16) u16 sU[64*SHS];   // 33792B
  __shared__ float sred[4][64];

  const int l  = threadIdx.x & 63;
  const int w  = threadIdx.x >> 6;
  const int q  = l >> 4;
  const int ml = l & 15;
  const long rowBase = (long)blockIdx.x * 64;

  // ---- stage BE tile once (frag layout) ----
  const u16* gA = BE + (size_t)(rowBase + w*16 + ml)*HD + q*8;
#pragma unroll
  for (int c=0; c<8; ++c) dma16(gA + c*32, sU + (c*4+w)*512);
  __syncthreads();

  ffrag acc[4][4];
#pragma unroll
  for (int mt=0; mt<4; ++mt)
#pragma unroll
    for (int n=0; n<4; ++n) acc[mt][n] = (ffrag){0.f,0.f,0.f,0.f};

  // ---- GEMM1 (barrier-free): A = sU frag, B = w1cf global ----
#pragma unroll 1
  for (int c=0; c<8; ++c){
    bfrag a[4], b[4];
#pragma unroll
    for (int n=0; n<4; ++n)
      b[n] = *(const bfrag*)(w1cf + (((size_t)c*16 + w*4 + n)*64 + l)*8);
#pragma unroll
    for (int mt=0; mt<4; ++mt) a[mt] = *(const bfrag*)(sU + (c*4+mt)*512 + l*8);
#pragma unroll
    for (int mt=0; mt<4; ++mt)
#pragma unroll
      for (int n=0; n<4; ++n)
        acc[mt][n] = __builtin_amdgcn_mfma_f32_16x16x32_bf16(a[mt], b[n], acc[mt][n], 0, 0, 0);
  }
  __syncthreads();   // all sU(frag) reads done before overwrite

  // ---- epilogue1: h -> sU row-major-264 ----
#pragma unroll
  for (int mt=0; mt<4; ++mt)
#pragma unroll
    for (int r=0; r<4; ++r){
      long row = rowBase + mt*16 + q*4 + r;
      const int si = srcI[row];
      const int ri = recvI[row];
      uint2 pu = *(const uint2*)(Pg + (size_t)si*HD + w*64 + ml*4);
      uint2 qu = *(const uint2*)(Qg + (size_t)ri*HD + w*64 + ml*4);
      u16 o[4];
      float pv[4] = { bf2f((u16)(pu.x & 0xffff)), bf2f((u16)(pu.x >> 16)),
                      bf2f((u16)(pu.y & 0xffff)), bf2f((u16)(pu.y >> 16)) };
      float qv[4] = { bf2f((u16)(qu.x & 0xffff)), bf2f((u16)(qu.x >> 16)),
                      bf2f((u16)(qu.y & 0xffff)), bf2f((u16)(qu.y >> 16)) };
#pragma unroll
      for (int n=0; n<4; ++n)
        o[n] = f2bf(fmaxf(acc[mt][n][r] + pv[n] + qv[n], 0.f));
      uint2 pk; pk.x = (u32)o[0] | ((u32)o[1]<<16); pk.y = (u32)o[2] | ((u32)o[3]<<16);
      *(uint2*)(sU + (size_t)(mt*16 + q*4 + r)*SHS + w*64 + ml*4) = pk;
    }
  __syncthreads();

  // ---- GEMM2 (barrier-free): A = sU row-major, B = w2f global ----
#pragma unroll
  for (int mt=0; mt<4; ++mt)
#pragma unroll
    for (int n=0; n<4; ++n) acc[mt][n] = (ffrag){0.f,0.f,0.f,0.f};
#pragma unroll 1
  for (int c=0; c<8; ++c){
    bfrag a[4], b[4];
#pragma unroll
    for (int n=0; n<4; ++n)
      b[n] = *(const bfrag*)(w2f + (((size_t)c*16 + w*4 + n)*64 + l)*8);
#pragma unroll
    for (int mt=0; mt<4; ++mt)
      a[mt] = *(const bfrag*)(sU + (size_t)(mt*16+ml)*SHS + c*32 + q*8);
#pragma unroll
    for (int mt=0; mt<4; ++mt)
#pragma unroll
      for (int n=0; n<4; ++n)
        acc[mt][n] = __builtin_amdgcn_mfma_f32_16x16x32_bf16(a[mt], b[n], acc[mt][n], 0, 0, 0);
  }

  float bia2[4];
#pragma unroll
  for (int n=0; n<4; ++n) bia2[n] = b2[(w*4+n)*16+ml];

  if constexpr (!LAST){
    __syncthreads();   // all sU reads of GEMM2 done before overwrite
    // epilogue2: b_e' -> global BE (in-place) + sU row-major for GEMM3
#pragma unroll
    for (int mt=0; mt<4; ++mt)
#pragma unroll
      for (int r=0; r<4; ++r){
        long row = rowBase + mt*16 + q*4 + r;
        u16 o[4];
#pragma unroll
        for (int n=0; n<4; ++n) o[n] = f2bf(acc[mt][n][r] + bia2[n]);
        uint2 pk; pk.x = (u32)o[0] | ((u32)o[1]<<16); pk.y = (u32)o[2] | ((u32)o[3]<<16);
        *(uint2*)(BE + (size_t)row*HD + w*64 + ml*4) = pk;
        *(uint2*)(sU + (size_t)(mt*16 + q*4 + r)*SHS + w*64 + ml*4) = pk;
      }
    __syncthreads();

    // ---- GEMM3 (barrier-free): A = sU row-major, B = eaw1f global ----
#pragma unroll
    for (int mt=0; mt<4; ++mt)
#pragma unroll
      for (int n=0; n<4; ++n) acc[mt][n] = (ffrag){0.f,0.f,0.f,0.f};
#pragma unroll 1
    for (int c=0; c<8; ++c){
      bfrag a[4], b[4];
#pragma unroll
      for (int n=0; n<4; ++n)
        b[n] = *(const bfrag*)(eaw1f + (((size_t)c*16 + w*4 + n)*64 + l)*8);
#pragma unroll
      for (int mt=0; mt<4; ++mt)
        a[mt] = *(const bfrag*)(sU + (size_t)(mt*16+ml)*SHS + c*32 + q*8);
#pragma unroll
      for (int mt=0; mt<4; ++mt)
#pragma unroll
        for (int n=0; n<4; ++n)
          acc[mt][n] = __builtin_amdgcn_mfma_f32_16x16x32_bf16(a[mt], b[n], acc[mt][n], 0, 0, 0);
    }
    float part[4][4];
#pragma unroll
    for (int mt=0; mt<4; ++mt)
#pragma unroll
      for (int r=0; r<4; ++r) part[mt][r] = 0.f;
#pragma unroll
    for (int n=0; n<4; ++n){
      const int col = (w*4+n)*16+ml;
      const float bb = sb1[col], vvn = sv[col];
#pragma unroll
      for (int mt=0; mt<4; ++mt)
#pragma unroll
        for (int r=0; r<4; ++r)
          part[mt][r] += fmaxf(acc[mt][n][r] + bb, 0.f) * vvn;
    }
#pragma unroll
    for (int mt=0; mt<4; ++mt)
#pragma unroll
      for (int r=0; r<4; ++r){
        float p = part[mt][r];
        p += __shfl_xor(p, 1, 64); p += __shfl_xor(p, 2, 64);
        p += __shfl_xor(p, 4, 64); p += __shfl_xor(p, 8, 64);
        part[mt][r] = p;
      }
    if (ml == 0)
#pragma unroll
      for (int mt=0; mt<4; ++mt)
#pragma unroll
        for (int r=0; r<4; ++r)
          sred[w][mt*16 + q*4 + r] = part[mt][r];
    __syncthreads();
    if (threadIdx.x < 64){
      const int t = threadIdx.x;
      float v = sred[0][t] + sred[1][t] + sred[2][t] + sred[3][t];
      scoreOut[rowBase + t] = sigmoidf(v + ssc[0]);
    }
  } else {
    // last iter: w_e = sigmoid(b_e' . ew_w + ew_b)
    float part[4][4];
#pragma unroll
    for (int mt=0; mt<4; ++mt)
#pragma unroll
      for (int r=0; r<4; ++r) part[mt][r] = 0.f;
#pragma unroll
    for (int n=0; n<4; ++n){
      const float vvn = wv[(w*4+n)*16+ml];
#pragma unroll
      for (int mt=0; mt<4; ++mt)
#pragma unroll
        for (int r=0; r<4; ++r)
          part[mt][r] += (acc[mt][n][r] + bia2[n]) * vvn;
    }
#pragma unroll
    for (int mt=0; mt<4; ++mt)
#pragma unroll
      for (int r=0; r<4; ++r){
        float p = part[mt][r];
        p += __shfl_xor(p, 1, 64); p += __shfl_xor(p, 2, 64);
        p += __shfl_xor(p, 4, 64); p += __shfl_xor(p, 8, 64);
        part[mt][r] = p;
      }
    if (ml == 0)
#pragma unroll
      for (int mt=0; mt<4; ++mt)
#pragma unroll
        for (int r=0; r<4; ++r)
          sred[w][mt*16 + q*4 + r] = part[mt][r];
    __syncthreads();
    if (threadIdx.x < 64){
      const int t = threadIdx.x;
      float v = sred[0][t] + sred[1][t] + sred[2][t] + sred[3][t];
      weOut[rowBase + t] = sigmoidf(v + wb[0]);
    }
  }
}

// repack B[256 x 256] f32 row-major -> bf16 frag layout [c][n][lane][8],
// K-rows permuted: packed row kp takes source feature inv(kp).
__global__ void repack_k(const float* __restrict__ B, u16* __restrict__ out){
  int t = blockIdx.x*256 + threadIdx.x;        // 8192 total
  int l = t & 63, n = (t>>6)&15, c = t>>10;
  int col = n*16 + (l&15);
  int kbase = c*32 + ((l>>4)<<3);
#pragma unroll
  for (int j=0; j<8; ++j){
    int kp = kbase + j;
    int f = (kp>>6)*64 + (kp&3)*16 + ((kp>>2)&15);   // inv(kp)
    out[(size_t)t*8 + j] = f2bf(B[(size_t)f*HD + col]);
  }
}

// b_e(iter0) = [edge_features | g_all] -> bf16, position-permuted layout
__global__ void initbe_k(const float* __restrict__ ef, const float* __restrict__ gall,
                         u16* __restrict__ BE){
  int t = blockIdx.x*256 + threadIdx.x;        // NE*64
  int e = t >> 6; int p4 = (t & 63) * 4;
  int w64 = p4 >> 6, mlr = (p4 >> 2) & 15;
  u16 o[4];
#pragma unroll
  for (int i=0; i<4; ++i){
    int f = w64*64 + i*16 + mlr;                 // inv(p4+i)
    float v = (f < 192) ? ef[(size_t)e*192 + f] : gall[f - 192];
    o[i] = f2bf(v);
  }
  uint2 pk; pk.x = (u32)o[0] | ((u32)o[1]<<16); pk.y = (u32)o[2] | ((u32)o[3]<<16);
  *(uint2*)(BE + (size_t)e*HD + p4) = pk;
}

__global__ void flags_k(const int* __restrict__ batch, const int* __restrict__ heads,
                        const int* __restrict__ tails, float* __restrict__ flags){
  int n = blockIdx.x*256 + threadIdx.x;
  int g = batch[n];
  flags[2*n]   = (n == heads[g]) ? 1.f : 0.f;
  flags[2*n+1] = (n == tails[g]) ? 1.f : 0.f;
}

// exclusive prefix sum of degrees -> CSR offsets (+ cursor copy), single block
__global__ void scan_k(const int* __restrict__ deg, int* __restrict__ offs,
                       int* __restrict__ cur){
  __shared__ int part[256];
  int tid = threadIdx.x;
  int base = tid * 64;
  int s = 0;
  for (int j=0; j<64; ++j) s += deg[base+j];
  part[tid] = s;
  __syncthreads();
  if (tid == 0){
    int run = 0;
    for (int i=0; i<256; ++i){ int t = part[i]; part[i] = run; run += t; }
  }
  __syncthreads();
  int run = part[tid];
  for (int j=0; j<64; ++j){
    offs[base+j] = run; cur[base+j] = run; run += deg[base+j];
  }
  if (tid == 255) offs[NN] = run;
}

__global__ void fill_k(const int* __restrict__ recv, int* __restrict__ cur,
                       int* __restrict__ eids){
  int e = blockIdx.x*256 + threadIdx.x;
  int r = recv[e];
  int p = atomicAdd(&cur[r], 1);
  eids[p] = e;
}

// per-node softmax over incoming edges + weighted aggregation, one wave per node
__global__ __launch_bounds__(256)
void agg_k(const float* __restrict__ score, const u16* __restrict__ BE,
           const int* __restrict__ offs, const int* __restrict__ eids,
           float* __restrict__ bv, u16* __restrict__ bvb){
  int node = blockIdx.x*4 + (threadIdx.x >> 6);
  int l = threadIdx.x & 63;
  int beg = offs[node], end = offs[node+1];

  float m = -1e30f;
  for (int i=beg+l; i<end; i+=64) m = fmaxf(m, score[eids[i]]);
#pragma unroll
  for (int d=1; d<64; d<<=1) m = fmaxf(m, __shfl_xor(m, d, 64));

  float s = 0.f;
  for (int i=beg+l; i<end; i+=64) s += __expf(score[eids[i]] - m);
#pragma unroll
  for (int d=1; d<64; d<<=1) s += __shfl_xor(s, d, 64);

  float deg = (float)(end - beg);
  float scale = (end > beg) ? (1.f/s) * (1.f/(1.f+deg)) : 0.f;

  float a0=0.f, a1=0.f, a2=0.f, a3=0.f;
  for (int i=beg; i<end; ++i){
    int e = eids[i];
    float al = __expf(score[e] - m);
    uint2 uv = *(const uint2*)(BE + (size_t)e*HD + l*4);
    a0 += al * bf2f((u16)(uv.x & 0xffff));
    a1 += al * bf2f((u16)(uv.x >> 16));
    a2 += al * bf2f((u16)(uv.y & 0xffff));
    a3 += al * bf2f((u16)(uv.y >> 16));
  }
  size_t o = (size_t)node*HD + l*4;
  a0 *= scale; a1 *= scale; a2 *= scale; a3 *= scale;
  bv[o+0]=a0; bv[o+1]=a1; bv[o+2]=a2; bv[o+3]=a3;
  uint2 p; p.x = (u32)f2bf(a0) | ((u32)f2bf(a1)<<16);
  p.y = (u32)f2bf(a2) | ((u32)f2bf(a3)<<16);
  *(uint2*)(bvb + o) = p;
}

// graph head: g_max + gather head/tail rows -> g_G [64][768] f32 (position space)
__global__ void gmax_k(const float* __restrict__ bv, const int* __restrict__ heads,
                       const int* __restrict__ tails, float* __restrict__ gG){
  int g = blockIdx.x, col = threadIdx.x;
  float mx = -1e30f;
  const float* p = bv + (size_t)g*256*HD + col;
  for (int i=0; i<256; ++i) mx = fmaxf(mx, p[(size_t)i*HD]);
  gG[g*768 + col]       = mx;
  gG[g*768 + 256 + col] = bv[(size_t)heads[g]*HD + col];
  gG[g*768 + 512 + col] = bv[(size_t)tails[g]*HD + col];
}

__global__ void glog_k(const float* __restrict__ gG, const float* __restrict__ w1,
                       const float* __restrict__ b1, const float* __restrict__ w2,
                       const float* __restrict__ b2, float* __restrict__ logits){
  int g = blockIdx.x, n = threadIdx.x;
  float a = b1[n];
  const float* gg = gG + g*768;
  for (int k=0; k<768; ++k){
    int b = k >> 8, p = k & 255;
    int f = (p>>6)*64 + (p&3)*16 + ((p>>2)&15);   // inv(p)
    a += gg[k] * w1[(size_t)(b*256 + f)*HD + n];
  }
  a = fmaxf(a, 0.f) * w2[n];
#pragma unroll
  for (int d=1; d<64; d<<=1) a += __shfl_xor(a, d, 64);
  __shared__ float red[4];
  if ((threadIdx.x & 63) == 0) red[threadIdx.x >> 6] = a;
  __syncthreads();
  if (threadIdx.x == 0) logits[g] = red[0]+red[1]+red[2]+red[3] + b2[0];
}

__global__ void gfin_k(const float* __restrict__ gG, const float* __restrict__ logits,
                       float* __restrict__ out){
  int tid = threadIdx.x;
  float m = -1e30f;
  for (int g=0; g<NG; ++g) m = fmaxf(m, logits[g]);
  float s = 0.f;
  for (int g=0; g<NG; ++g) s += __expf(logits[g] - m);
  float inv = 1.f/s;
  for (int j=tid; j<768; j+=256){
    int b = j >> 8, f = j & 255;
    int p = (f>>6)*64 + (f&15)*4 + ((f>>4)&3);    // pi(f): un-permute for output
    float o = 0.f;
    for (int g=0; g<NG; ++g) o += __expf(logits[g]-m)*inv * gG[g*768 + b*256 + p];
    out[j] = o;
  }
}

extern "C" void kernel_launch(void* const* d_in, const int* in_sizes, int n_in,
                              void* d_out, int out_size, void* d_ws, size_t ws_size,
                              hipStream_t stream)
{
  const float* ef    = (const float*)d_in[0];
  const float* gall  = (const float*)d_in[1];
  const float* ea_w1 = (const float*)d_in[2];
  const float* ea_b1 = (const float*)d_in[3];
  const float* ea_w2 = (const float*)d_in[4];
  const float* ea_b2 = (const float*)d_in[5];
  const float* eu_w1 = (const float*)d_in[6];
  const float* eu_b1 = (const float*)d_in[7];
  const float* eu_w2 = (const float*)d_in[8];
  const float* eu_b2 = (const float*)d_in[9];
  const float* gw_w1 = (const float*)d_in[10];
  const float* gw_b1 = (const float*)d_in[11];
  const float* gw_w2 = (const float*)d_in[12];
  const float* gw_b2 = (const float*)d_in[13];
  const float* ew_w  = (const float*)d_in[14];
  const float* ew_b  = (const float*)d_in[15];
  const int* eidx    = (const int*)d_in[16];
  const int* srcI    = eidx;
  const int* recvI   = eidx + NE;
  const int* ndeg    = (const int*)d_in[17];
  const int* batch   = (const int*)d_in[18];
  const int* heads   = (const int*)d_in[19];
  const int* tails   = (const int*)d_in[20];
  float* out = (float*)d_out;

  char* wsb = (char*)d_ws;
  size_t off = 0;
  auto alloc = [&](size_t sz)->char*{
    char* p = wsb + off; off = (off + sz + 255) & ~(size_t)255; return p;
  };
  u16*   BE    = (u16*)  alloc((size_t)NE*HD*2);
  float* score = (float*)alloc((size_t)NE*4);
  u16*   P     = (u16*)  alloc((size_t)NN*HD*2);
  u16*   Q     = (u16*)  alloc((size_t)NN*HD*2);
  float* bv    = (float*)alloc((size_t)NN*HD*4);
  u16*   bvb   = (u16*)  alloc((size_t)NN*HD*2);
  int*   offs  = (int*)  alloc((size_t)(NN+1)*4);
  int*   cur   = (int*)  alloc((size_t)NN*4);
  int*   eids  = (int*)  alloc((size_t)NE*4);
  float* flags = (float*)alloc((size_t)NN*8);
  u16*   eaw1f = (u16*)  alloc((size_t)65536*2);
  u16*   w1af  = (u16*)  alloc((size_t)65536*2);
  u16*   w1bf  = (u16*)  alloc((size_t)65536*2);
  u16*   w1cf  = (u16*)  alloc((size_t)65536*2);
  u16*   euw2f = (u16*)  alloc((size_t)65536*2);
  float* gG    = (float*)alloc((size_t)NG*768*4);
  float* logits= (float*)alloc((size_t)NG*4);

  // one-time per launch: weight repacks + b_e init + flags + CSR
  repack_k<<<32,256,0,stream>>>(ea_w1, eaw1f);
  repack_k<<<32,256,0,stream>>>(eu_w1, w1af);              // rows 0..255   (src b_v part)
  repack_k<<<32,256,0,stream>>>(eu_w1 + 258*HD, w1bf);     // rows 258..513 (recv b_v part)
  repack_k<<<32,256,0,stream>>>(eu_w1 + 516*HD, w1cf);     // rows 516..771 (b_e part)
  repack_k<<<32,256,0,stream>>>(eu_w2, euw2f);
  initbe_k<<<NE*64/256,256,0,stream>>>(ef, gall, BE);
  flags_k<<<NN/256,256,0,stream>>>(batch, heads, tails, flags);
  scan_k<<<1,256,0,stream>>>(ndeg, offs, cur);
  fill_k<<<NE/256,256,0,stream>>>(recvI, cur, eids);

  // score for iter0 (reads the freshly-built BE)
  gemm_k<MODE_SCORE><<<NE/64,256,0,stream>>>(BE, eaw1f, nullptr, score,
      nullptr, nullptr, ea_b1, ea_w2, ea_b2, nullptr, nullptr, nullptr);

  for (int it=0; it<3; ++it){
    // scatter-softmax + degree-normalized aggregation -> b_v (f32 + bf16)
    agg_k<<<NN/4,256,0,stream>>>(score, BE, offs, eids, bv, bvb);
    // P = r_v@W1a + b1 ; Q = r_v@W1b (one dispatch, grid.y selects half)
    gemm_k<MODE_PQ><<<dim3(NN/64,2),256,0,stream>>>(bvb, w1af, w1bf, nullptr,
        P, Q, eu_b1, nullptr, nullptr, flags, eu_w1 + 256*HD, eu_w1 + 514*HD);
    // fused edge update (+ next score, or final w_e)
    if (it < 2){
      mega_k<false><<<NE/64,256,0,stream>>>(BE, w1cf, euw2f, eaw1f,
          score, nullptr, P, Q, srcI, recvI, eu_b2,
          ea_b1, ea_w2, ea_b2, nullptr, nullptr);
    } else {
      mega_k<true><<<NE/64,256,0,stream>>>(BE, w1cf, euw2f, eaw1f,
          nullptr, out, P, Q, srcI, recvI, eu_b2,
          nullptr, nullptr, nullptr, ew_w, ew_b);
    }
  }

  // graph head (f32 exact, tiny; un-permutes positions)
  gmax_k<<<NG,256,0,stream>>>(bv, heads, tails, gG);
  glog_k<<<NG,256,0,stream>>>(gG, gw_w1, gw_b1, gw_w2, gw_b2, logits);
  gfin_k<<<1,256,0,stream>>>(gG, logits, out + NE);
}